// Round 6
// baseline (1960.014 us; speedup 1.0000x reference)
//
#include <hip/hip_runtime.h>
#include <math.h>

typedef __attribute__((ext_vector_type(8))) short bf16x8;
typedef __attribute__((ext_vector_type(4))) float f32x4;

__device__ inline unsigned short f2bf(float f) {
    unsigned int u = __float_as_uint(f);
    unsigned int r = u + 0x7fffu + ((u >> 16) & 1u);
    return (unsigned short)(r >> 16);
}
__device__ inline float bf2f(unsigned short b) {
    return __uint_as_float(((unsigned int)b) << 16);
}

// ---------------- CSR build (union graph: nodes [0,N)=g1, [N,2N)=g2) ----------------

__global__ void histU_kernel(const int* __restrict__ d1, const int* __restrict__ d2,
                             int* __restrict__ cnt, int E, int N) {
    int i = blockIdx.x * blockDim.x + threadIdx.x;
    if (i < E) atomicAdd(&cnt[d1[i]], 1);
    else if (i < 2 * E) atomicAdd(&cnt[N + d2[i - E]], 1);
}

__global__ __launch_bounds__(256) void block_reduce_kernel(const int* __restrict__ cnt,
                                                           float* __restrict__ dinv,
                                                           int* __restrict__ blockSums, int NN) {
    int i = blockIdx.x * 256 + threadIdx.x;
    int v = 0;
    if (i < NN) {
        v = cnt[i];
        dinv[i] = 1.0f / sqrtf((float)(v + 1));  // +1 self loop
    }
    int s = v;
#pragma unroll
    for (int o = 32; o; o >>= 1) s += __shfl_down(s, o);
    __shared__ int ws[4];
    if ((threadIdx.x & 63) == 0) ws[threadIdx.x >> 6] = s;
    __syncthreads();
    if (threadIdx.x == 0) blockSums[blockIdx.x] = ws[0] + ws[1] + ws[2] + ws[3];
}

__global__ __launch_bounds__(1024) void scan_sums_kernel(const int* __restrict__ blockSums,
                                                         int* __restrict__ blockOff, int nb,
                                                         int* __restrict__ rowptr, int NN) {
    __shared__ int sh[1024];
    int t = threadIdx.x;
    int v = (t < nb) ? blockSums[t] : 0;
    sh[t] = v;
    __syncthreads();
    for (int o = 1; o < 1024; o <<= 1) {
        int u = (t >= o) ? sh[t - o] : 0;
        __syncthreads();
        sh[t] += u;
        __syncthreads();
    }
    if (t < nb) blockOff[t] = sh[t] - v;
    if (t == 1023) rowptr[NN] = sh[1023];
}

__global__ __launch_bounds__(256) void scan_write_kernel(const int* __restrict__ cnt,
                                                         const int* __restrict__ blockOff,
                                                         int* __restrict__ rowptr, int NN) {
    __shared__ int sh[256];
    int i = blockIdx.x * 256 + threadIdx.x;
    int t = threadIdx.x;
    int v = (i < NN) ? cnt[i] : 0;
    sh[t] = v;
    __syncthreads();
    for (int o = 1; o < 256; o <<= 1) {
        int u = (t >= o) ? sh[t - o] : 0;
        __syncthreads();
        sh[t] += u;
        __syncthreads();
    }
    if (i < NN) rowptr[i] = blockOff[blockIdx.x] + sh[t] - v;
}

__global__ void placeU_kernel(const int* __restrict__ s1, const int* __restrict__ d1,
                              const int* __restrict__ s2, const int* __restrict__ d2,
                              const int* __restrict__ rowptr, int* __restrict__ cnt,
                              int* __restrict__ csr, int E, int N) {
    int i = blockIdx.x * blockDim.x + threadIdx.x;
    int s, d;
    if (i < E)          { s = s1[i];         d = d1[i]; }
    else if (i < 2 * E) { s = s2[i - E] + N; d = d2[i - E] + N; }
    else return;
    int p = atomicSub(&cnt[d], 1);  // old count, 1..deg; drains cnt to 0
    csr[rowptr[d] + p - 1] = s;
}

// ---------------- Weight prep: W[K][128] f32 -> WhT/WlT [128][K] bf16 ----------------

__global__ void prep_weights(const float* __restrict__ W0, const float* __restrict__ W1,
                             const float* __restrict__ W2,
                             unsigned short* __restrict__ W0h, unsigned short* __restrict__ W0l,
                             unsigned short* __restrict__ W1h, unsigned short* __restrict__ W1l,
                             unsigned short* __restrict__ W2h, unsigned short* __restrict__ W2l) {
    const float* W; unsigned short *Wh, *Wl; int K;
    if (blockIdx.x == 0)      { W = W0; Wh = W0h; Wl = W0l; K = 64; }
    else if (blockIdx.x == 1) { W = W1; Wh = W1h; Wl = W1l; K = 128; }
    else                      { W = W2; Wh = W2h; Wl = W2l; K = 128; }
    for (int i = threadIdx.x; i < K * 128; i += 256) {
        int k = i >> 7, c = i & 127;
        float v = W[i];
        unsigned short h = f2bf(v);
        unsigned short l = f2bf(v - bf2f(h));
        Wh[c * K + k] = h;
        Wl[c * K + k] = l;
    }
}

// ---- Transpose + dinv fold: x1,x2 [node][64] -> X0sl [8][NN][8] f32, row *= dinv ----
// lane&7 = slice, 8 lanes per node: reads fully coalesced (2KB/wave), writes 256B chunks.

__global__ __launch_bounds__(256) void xpose_kernel(const float* __restrict__ x1,
                                                    const float* __restrict__ x2,
                                                    const float* __restrict__ dinv,
                                                    float* __restrict__ X0sl, int NN, int N) {
    int t = threadIdx.x;
    int node = blockIdx.x * 32 + (t >> 3);
    int sf = t & 7;
    if (node >= NN) return;
    const float* xr = (node < N) ? (x1 + (size_t)node * 64) : (x2 + (size_t)(node - N) * 64);
    float d = dinv[node];
    float4 a = *reinterpret_cast<const float4*>(xr + sf * 8);
    float4 b = *reinterpret_cast<const float4*>(xr + sf * 8 + 4);
    a.x *= d; a.y *= d; a.z *= d; a.w *= d;
    b.x *= d; b.y *= d; b.z *= d; b.w *= d;
    float* o = X0sl + ((size_t)sf * NN + node) * 8;
    *reinterpret_cast<float4*>(o) = a;
    *reinterpret_cast<float4*>(o + 4) = b;
}

// ---- Sliced aggregation: per slice s (8 feats), S[s][i] = X[s][i] + sum_{src} X[s][src] ----
// slice = blockIdx&7 pins one slice per XCD (round-robin dispatch) -> 3.2MB slice is
// L2-resident; csr streamed with nontemporal loads. 8-lane group owns one node.

__global__ __launch_bounds__(256) void agg_slice_kernel(
    const float* __restrict__ Xsl, const int* __restrict__ rowptr,
    const int* __restrict__ csr,
    unsigned short* __restrict__ Shi, unsigned short* __restrict__ Slo,
    int NN, int nchunks) {
    int b = blockIdx.x;
    int sgroup = b / (8 * nchunks);
    int rem = b - sgroup * 8 * nchunks;
    int slice = (rem & 7) + 8 * sgroup;
    int chunk = rem >> 3;
    int t = threadIdx.x;
    int feat = t & 7;
    int g = t >> 3;  // 0..31

    const float* Xs = Xsl + (size_t)slice * NN * 8;
    unsigned short* Hh = Shi + (size_t)slice * NN * 8;
    unsigned short* Hl = Slo + (size_t)slice * NN * 8;

    for (int it = 0; it < 512; it += 32) {
        int base = chunk * 512 + it;
        if (base >= NN) break;
        int node = base + g;
        bool alive = node < NN;
        int beg = 0, deg = 0;
        if (alive) {
            beg = rowptr[node];
            deg = rowptr[node + 1] - beg;
        }
        float acc = alive ? Xs[(size_t)node * 8 + feat] : 0.f;  // self term
        for (int k = 0; k < deg; k += 8) {
#pragma unroll
            for (int j = 0; j < 8; ++j) {
                int idx = k + j;
                if (idx < deg) {
                    int s = __builtin_nontemporal_load(csr + beg + idx);
                    acc += Xs[(size_t)s * 8 + feat];
                }
            }
        }
        if (alive) {
            unsigned short h = f2bf(acc);
            Hh[(size_t)node * 8 + feat] = h;
            Hl[(size_t)node * 8 + feat] = f2bf(acc - bf2f(h));
        }
    }
}

// ---- MFMA GEMM from slice-major split-bf16 A. BM=64, 512 thr (8 waves, 16 cols each).
// mode 1: C sliced [sf][node][8] f32, post-scaled by dinv. mode 0: row-major, no post.

template <int K>
__global__ __launch_bounds__(512) void gemm_mfma(const unsigned short* __restrict__ Ah,
                                                 const unsigned short* __restrict__ Al,
                                                 const unsigned short* __restrict__ WhT,
                                                 const unsigned short* __restrict__ WlT,
                                                 const float* __restrict__ bias,
                                                 const float* __restrict__ dinv, int mode,
                                                 float* __restrict__ C, int M) {
    const int LDA = K + 8;
    __shared__ unsigned short ldsH[64 * LDA];
    __shared__ unsigned short ldsL[64 * LDA];

    int t = threadIdx.x;
    int lane = t & 63, wid = t >> 6;
    int c16 = lane & 15, kq = (lane >> 4) * 8;
    int row0 = blockIdx.x * 64;
    int col = wid * 16 + c16;

    bf16x8 wh[K / 32], wl[K / 32];
#pragma unroll
    for (int ks = 0; ks < K / 32; ++ks) {
        wh[ks] = *reinterpret_cast<const bf16x8*>(WhT + (size_t)col * K + ks * 32 + kq);
        wl[ks] = *reinterpret_cast<const bf16x8*>(WlT + (size_t)col * K + ks * 32 + kq);
    }

    const int CH = 64 * (K / 8);
    for (int c = t; c < CH; c += 512) {
        int row = c & 63, sf = c >> 6;   // consecutive threads -> consecutive rows (coalesced)
        int gr = row0 + row; if (gr >= M) gr = M - 1;
        size_t ga = ((size_t)sf * M + gr) * 8;
        *reinterpret_cast<bf16x8*>(&ldsH[row * LDA + sf * 8]) =
            *reinterpret_cast<const bf16x8*>(Ah + ga);
        *reinterpret_cast<bf16x8*>(&ldsL[row * LDA + sf * 8]) =
            *reinterpret_cast<const bf16x8*>(Al + ga);
    }
    __syncthreads();

    float bb = bias[col];
#pragma unroll
    for (int rt = 0; rt < 4; ++rt) {
        f32x4 acc = {0.f, 0.f, 0.f, 0.f};
        int abase = (rt * 16 + c16) * LDA + kq;
#pragma unroll
        for (int ks = 0; ks < K / 32; ++ks) {
            bf16x8 ah = *reinterpret_cast<const bf16x8*>(ldsH + abase + ks * 32);
            bf16x8 al = *reinterpret_cast<const bf16x8*>(ldsL + abase + ks * 32);
            acc = __builtin_amdgcn_mfma_f32_16x16x32_bf16(ah, wh[ks], acc, 0, 0, 0);
            acc = __builtin_amdgcn_mfma_f32_16x16x32_bf16(ah, wl[ks], acc, 0, 0, 0);
            acc = __builtin_amdgcn_mfma_f32_16x16x32_bf16(al, wh[ks], acc, 0, 0, 0);
        }
#pragma unroll
        for (int r = 0; r < 4; ++r) {
            int gr = row0 + rt * 16 + (lane >> 4) * 4 + r;
            if (gr < M) {
                float d = dinv[gr];
                if (mode) {
                    float v = fmaxf(acc[r] * d + bb, 0.f) * d;
                    C[((size_t)(col >> 3) * M + gr) * 8 + (col & 7)] = v;
                } else {
                    float v = fmaxf(acc[r] * d + bb, 0.f);
                    C[(size_t)gr * 128 + col] = v;
                }
            }
        }
    }
}

// ---------------- Final FC ----------------

__global__ void fc_kernel(const float* __restrict__ H3, const int* __restrict__ label,
                          const float* __restrict__ fcW, const float* __restrict__ fcb,
                          float* __restrict__ out, int P, int N) {
    int w = blockIdx.x * (blockDim.x >> 6) + (threadIdx.x >> 6);
    int lane = threadIdx.x & 63;
    if (w >= P) return;
    int l0 = label[2 * w], l1 = label[2 * w + 1] + N;
    float xl0 = H3[(size_t)l0 * 128 + lane];
    float xl1 = H3[(size_t)l0 * 128 + 64 + lane];
    float xr0 = H3[(size_t)l1 * 128 + lane];
    float xr1 = H3[(size_t)l1 * 128 + 64 + lane];
    float a0 = xl0 * fcW[lane * 2]             + xl1 * fcW[(64 + lane) * 2]
             + xr0 * fcW[(128 + lane) * 2]     + xr1 * fcW[(192 + lane) * 2];
    float a1 = xl0 * fcW[lane * 2 + 1]         + xl1 * fcW[(64 + lane) * 2 + 1]
             + xr0 * fcW[(128 + lane) * 2 + 1] + xr1 * fcW[(192 + lane) * 2 + 1];
#pragma unroll
    for (int o = 32; o; o >>= 1) {
        a0 += __shfl_xor(a0, o);
        a1 += __shfl_xor(a1, o);
    }
    if (lane == 0) {
        out[2 * w]     = fmaxf(a0 + fcb[0], 0.f);
        out[2 * w + 1] = fmaxf(a1 + fcb[1], 0.f);
    }
}

// ---------------- launch ----------------

extern "C" void kernel_launch(void* const* d_in, const int* in_sizes, int n_in,
                              void* d_out, int out_size, void* d_ws, size_t ws_size,
                              hipStream_t stream) {
    const float* x1   = (const float*)d_in[0];
    const int*   e1   = (const int*)d_in[1];
    const float* x2   = (const float*)d_in[2];
    const int*   e2   = (const int*)d_in[3];
    const int*   label= (const int*)d_in[4];
    const float* W0   = (const float*)d_in[5];
    const float* b0   = (const float*)d_in[6];
    const float* W1   = (const float*)d_in[7];
    const float* b1   = (const float*)d_in[8];
    const float* W2   = (const float*)d_in[9];
    const float* b2   = (const float*)d_in[10];
    const float* fcW  = (const float*)d_in[11];
    const float* fcb  = (const float*)d_in[12];
    float* out = (float*)d_out;

    const int N = in_sizes[0] / 64;
    const int E = in_sizes[1] / 2;
    const int P = in_sizes[4] / 2;
    const int NN = 2 * N;
    const int NB = (NN + 255) / 256;
    const int NCH = (NN + 511) / 512;   // agg node chunks
    const int GB = (NN + 63) / 64;      // gemm blocks

    char* ws = (char*)d_ws;
    size_t off = 0;
    auto alloc = [&](size_t bytes) -> void* {
        void* p = ws + off;
        off += (bytes + 255) & ~(size_t)255;
        return p;
    };
    int*   cnt      = (int*)alloc((size_t)NN * 4);
    int*   rowptr   = (int*)alloc((size_t)(NN + 1) * 4);
    float* dinv     = (float*)alloc((size_t)NN * 4);
    int*   csr      = (int*)alloc((size_t)2 * E * 4);
    int*   blockSums= (int*)alloc((size_t)NB * 4);
    int*   blockOff = (int*)alloc((size_t)NB * 4);
    // Region A overlay: X0sl [8][NN][8] f32 (25.6MB) -> Xsl [16][NN][8] f32 (51.2MB) -> H3 row-major
    float* regA     = (float*)alloc((size_t)NN * 128 * 4);
    unsigned short* Shi = (unsigned short*)alloc((size_t)NN * 128 * 2);
    unsigned short* Slo = (unsigned short*)alloc((size_t)NN * 128 * 2);
    unsigned short* W0h = (unsigned short*)alloc(64 * 128 * 2);
    unsigned short* W0l = (unsigned short*)alloc(64 * 128 * 2);
    unsigned short* W1h = (unsigned short*)alloc(128 * 128 * 2);
    unsigned short* W1l = (unsigned short*)alloc(128 * 128 * 2);
    unsigned short* W2h = (unsigned short*)alloc(128 * 128 * 2);
    unsigned short* W2l = (unsigned short*)alloc(128 * 128 * 2);

    prep_weights<<<3, 256, 0, stream>>>(W0, W1, W2, W0h, W0l, W1h, W1l, W2h, W2l);

    // CSR build (once, union graph)
    hipMemsetAsync(cnt, 0, (size_t)NN * 4, stream);
    histU_kernel<<<(2 * E + 255) / 256, 256, 0, stream>>>(e1 + E, e2 + E, cnt, E, N);
    block_reduce_kernel<<<NB, 256, 0, stream>>>(cnt, dinv, blockSums, NN);
    scan_sums_kernel<<<1, 1024, 0, stream>>>(blockSums, blockOff, NB, rowptr, NN);
    scan_write_kernel<<<NB, 256, 0, stream>>>(cnt, blockOff, rowptr, NN);
    placeU_kernel<<<(2 * E + 255) / 256, 256, 0, stream>>>(e1, e1 + E, e2, e2 + E,
                                                           rowptr, cnt, csr, E, N);
    // layer 0: transpose+prescale x -> X0sl; sliced agg (8 slices); GEMM 64->128
    xpose_kernel<<<(NN + 31) / 32, 256, 0, stream>>>(x1, x2, dinv, regA, NN, N);
    agg_slice_kernel<<<8 * NCH, 256, 0, stream>>>(regA, rowptr, csr, Shi, Slo, NN, NCH);
    gemm_mfma<64><<<GB, 512, 0, stream>>>(Shi, Slo, W0h, W0l, b0, dinv, 1, regA, NN);
    // layer 1: sliced agg (16 slices); GEMM 128->128
    agg_slice_kernel<<<16 * NCH, 256, 0, stream>>>(regA, rowptr, csr, Shi, Slo, NN, NCH);
    gemm_mfma<128><<<GB, 512, 0, stream>>>(Shi, Slo, W1h, W1l, b1, dinv, 1, regA, NN);
    // layer 2: sliced agg; final GEMM writes row-major H3 (mode 0, no post-scale)
    agg_slice_kernel<<<16 * NCH, 256, 0, stream>>>(regA, rowptr, csr, Shi, Slo, NN, NCH);
    gemm_mfma<128><<<GB, 512, 0, stream>>>(Shi, Slo, W2h, W2l, b2, dinv, 0, regA, NN);

    fc_kernel<<<(P + 3) / 4, 256, 0, stream>>>(regA, label, fcW, fcb, out, P, N);
}

// Round 7
// 651.535 us; speedup vs baseline: 3.0083x; 3.0083x over previous
//
#include <hip/hip_runtime.h>
#include <math.h>

typedef __attribute__((ext_vector_type(8))) short bf16x8;
typedef __attribute__((ext_vector_type(4))) float f32x4;

__device__ inline unsigned short f2bf(float f) {
    unsigned int u = __float_as_uint(f);
    unsigned int r = u + 0x7fffu + ((u >> 16) & 1u);
    return (unsigned short)(r >> 16);
}
__device__ inline float bf2f(unsigned short b) {
    return __uint_as_float(((unsigned int)b) << 16);
}

// ---------------- CSR build (union graph: nodes [0,N)=g1, [N,2N)=g2) ----------------

__global__ void histU_kernel(const int* __restrict__ d1, const int* __restrict__ d2,
                             int* __restrict__ cnt, int E, int N) {
    int i = blockIdx.x * blockDim.x + threadIdx.x;
    if (i < E) atomicAdd(&cnt[d1[i]], 1);
    else if (i < 2 * E) atomicAdd(&cnt[N + d2[i - E]], 1);
}

__global__ __launch_bounds__(256) void block_reduce_kernel(const int* __restrict__ cnt,
                                                           float* __restrict__ dinv,
                                                           int* __restrict__ blockSums, int NN) {
    int i = blockIdx.x * 256 + threadIdx.x;
    int v = 0;
    if (i < NN) {
        v = cnt[i];
        dinv[i] = 1.0f / sqrtf((float)(v + 1));  // +1 self loop
    }
    int s = v;
#pragma unroll
    for (int o = 32; o; o >>= 1) s += __shfl_down(s, o);
    __shared__ int ws[4];
    if ((threadIdx.x & 63) == 0) ws[threadIdx.x >> 6] = s;
    __syncthreads();
    if (threadIdx.x == 0) blockSums[blockIdx.x] = ws[0] + ws[1] + ws[2] + ws[3];
}

__global__ __launch_bounds__(1024) void scan_sums_kernel(const int* __restrict__ blockSums,
                                                         int* __restrict__ blockOff, int nb,
                                                         int* __restrict__ rowptr, int NN) {
    __shared__ int sh[1024];
    int t = threadIdx.x;
    int v = (t < nb) ? blockSums[t] : 0;
    sh[t] = v;
    __syncthreads();
    for (int o = 1; o < 1024; o <<= 1) {
        int u = (t >= o) ? sh[t - o] : 0;
        __syncthreads();
        sh[t] += u;
        __syncthreads();
    }
    if (t < nb) blockOff[t] = sh[t] - v;
    if (t == 1023) rowptr[NN] = sh[1023];
}

__global__ __launch_bounds__(256) void scan_write_kernel(const int* __restrict__ cnt,
                                                         const int* __restrict__ blockOff,
                                                         int* __restrict__ rowptr, int NN) {
    __shared__ int sh[256];
    int i = blockIdx.x * 256 + threadIdx.x;
    int t = threadIdx.x;
    int v = (i < NN) ? cnt[i] : 0;
    sh[t] = v;
    __syncthreads();
    for (int o = 1; o < 256; o <<= 1) {
        int u = (t >= o) ? sh[t - o] : 0;
        __syncthreads();
        sh[t] += u;
        __syncthreads();
    }
    if (i < NN) rowptr[i] = blockOff[blockIdx.x] + sh[t] - v;
}

__global__ void placeU_kernel(const int* __restrict__ s1, const int* __restrict__ d1,
                              const int* __restrict__ s2, const int* __restrict__ d2,
                              const int* __restrict__ rowptr, int* __restrict__ cnt,
                              int* __restrict__ csr, int E, int N) {
    int i = blockIdx.x * blockDim.x + threadIdx.x;
    int s, d;
    if (i < E)          { s = s1[i];         d = d1[i]; }
    else if (i < 2 * E) { s = s2[i - E] + N; d = d2[i - E] + N; }
    else return;
    int p = atomicSub(&cnt[d], 1);  // old count, 1..deg; drains cnt to 0
    csr[rowptr[d] + p - 1] = s;
}

// ---------------- Weight prep: W[K][128] f32 -> WhT/WlT [128][K] bf16 ----------------

__global__ void prep_weights(const float* __restrict__ W0, const float* __restrict__ W1,
                             const float* __restrict__ W2,
                             unsigned short* __restrict__ W0h, unsigned short* __restrict__ W0l,
                             unsigned short* __restrict__ W1h, unsigned short* __restrict__ W1l,
                             unsigned short* __restrict__ W2h, unsigned short* __restrict__ W2l) {
    const float* W; unsigned short *Wh, *Wl; int K;
    if (blockIdx.x == 0)      { W = W0; Wh = W0h; Wl = W0l; K = 64; }
    else if (blockIdx.x == 1) { W = W1; Wh = W1h; Wl = W1l; K = 128; }
    else                      { W = W2; Wh = W2h; Wl = W2l; K = 128; }
    for (int i = threadIdx.x; i < K * 128; i += 256) {
        int k = i >> 7, c = i & 127;
        float v = W[i];
        unsigned short h = f2bf(v);
        unsigned short l = f2bf(v - bf2f(h));
        Wh[c * K + k] = h;
        Wl[c * K + k] = l;
    }
}

// ------- Layer-0 aggregation from raw inputs, dinv folded; outputs split bf16 -------
// 16-deep predicated batches: 16 gathers in flight every round.

__global__ void agg64U_kernel(const float* __restrict__ x1, const float* __restrict__ x2,
                              const int* __restrict__ rowptr, const int* __restrict__ csr,
                              const float* __restrict__ dinv,
                              unsigned short* __restrict__ Shi, unsigned short* __restrict__ Slo,
                              int NN, int N) {
    int w = blockIdx.x * (blockDim.x >> 6) + (threadIdx.x >> 6);
    int lane = threadIdx.x & 63;
    if (w >= NN) return;
    int beg = rowptr[w], end = rowptr[w + 1];
    const float* selfrow = (w < N) ? (x1 + (size_t)w * 64) : (x2 + (size_t)(w - N) * 64);
    float acc = dinv[w] * selfrow[lane];
    for (int k = beg; k < end; k += 16) {
#pragma unroll
        for (int j = 0; j < 16; ++j) {
            int a = k + j;
            bool vld = a < end;
            int s = csr[vld ? a : beg];
            float wt = vld ? dinv[s] : 0.f;
            const float* r = (s < N) ? (x1 + (size_t)s * 64) : (x2 + (size_t)(s - N) * 64);
            acc += wt * r[lane];
        }
    }
    unsigned short h = f2bf(acc);
    Shi[(size_t)w * 64 + lane] = h;
    Slo[(size_t)w * 64 + lane] = f2bf(acc - bf2f(h));
}

// ------- Layers 1-2 aggregation: input f32 (pre-scaled), output split bf16 -------

__global__ void agg128_kernel(const float* __restrict__ Xf, const int* __restrict__ rowptr,
                              const int* __restrict__ csr,
                              unsigned short* __restrict__ Shi, unsigned short* __restrict__ Slo,
                              int NN) {
    int w = blockIdx.x * (blockDim.x >> 6) + (threadIdx.x >> 6);
    int lane = threadIdx.x & 63;
    if (w >= NN) return;
    const float2* X = (const float2*)Xf;
    int beg = rowptr[w], end = rowptr[w + 1];
    float2 self = X[(size_t)w * 64 + lane];
    float ax = self.x, ay = self.y;
    for (int k = beg; k < end; k += 16) {
#pragma unroll
        for (int j = 0; j < 16; ++j) {
            int a = k + j;
            bool vld = a < end;
            int s = csr[vld ? a : beg];
            float m = vld ? 1.f : 0.f;
            float2 v = X[(size_t)s * 64 + lane];
            ax += m * v.x; ay += m * v.y;
        }
    }
    unsigned short hx = f2bf(ax), hy = f2bf(ay);
    ushort2 H; H.x = hx; H.y = hy;
    ushort2 L; L.x = f2bf(ax - bf2f(hx)); L.y = f2bf(ay - bf2f(hy));
    *reinterpret_cast<ushort2*>(Shi + (size_t)w * 128 + 2 * lane) = H;
    *reinterpret_cast<ushort2*>(Slo + (size_t)w * 128 + 2 * lane) = L;
}

// ---- MFMA GEMM: C[r] = po(r)*relu(dinv[r]*(A@W)[r] + bias), A = Ah+Al (split bf16) ----
// BM=64, 512 threads = 8 waves; wave w owns cols [16w,16w+16). LDS 35KB -> 4 blocks/CU.

template <int K>
__global__ __launch_bounds__(512) void gemm_mfma(const unsigned short* __restrict__ Ah,
                                                 const unsigned short* __restrict__ Al,
                                                 const unsigned short* __restrict__ WhT,
                                                 const unsigned short* __restrict__ WlT,
                                                 const float* __restrict__ bias,
                                                 const float* __restrict__ dinv, int post,
                                                 float* __restrict__ C, int M) {
    const int LDA = K + 8;
    __shared__ unsigned short ldsH[64 * LDA];
    __shared__ unsigned short ldsL[64 * LDA];

    int t = threadIdx.x;
    int lane = t & 63, wid = t >> 6;
    int c16 = lane & 15, kq = (lane >> 4) * 8;
    int row0 = blockIdx.x * 64;
    int col = wid * 16 + c16;

    // W fragments for this wave's 16-col tile (L2-resident weights).
    bf16x8 wh[K / 32], wl[K / 32];
#pragma unroll
    for (int ks = 0; ks < K / 32; ++ks) {
        wh[ks] = *reinterpret_cast<const bf16x8*>(WhT + (size_t)col * K + ks * 32 + kq);
        wl[ks] = *reinterpret_cast<const bf16x8*>(WlT + (size_t)col * K + ks * 32 + kq);
    }

    // Stage A hi/lo tile: 64 rows x K bf16 each (coalesced 16B chunks).
    const int CH = 64 * (K / 8);
    for (int c = t; c < CH; c += 512) {
        int row = c / (K / 8), kb = c % (K / 8);
        int gr = row0 + row; if (gr >= M) gr = M - 1;
        *reinterpret_cast<bf16x8*>(&ldsH[row * LDA + kb * 8]) =
            *reinterpret_cast<const bf16x8*>(Ah + (size_t)gr * K + kb * 8);
        *reinterpret_cast<bf16x8*>(&ldsL[row * LDA + kb * 8]) =
            *reinterpret_cast<const bf16x8*>(Al + (size_t)gr * K + kb * 8);
    }
    __syncthreads();

    float bb = bias[col];
#pragma unroll
    for (int rt = 0; rt < 4; ++rt) {
        f32x4 acc = {0.f, 0.f, 0.f, 0.f};
        int abase = (rt * 16 + c16) * LDA + kq;
#pragma unroll
        for (int ks = 0; ks < K / 32; ++ks) {
            bf16x8 ah = *reinterpret_cast<const bf16x8*>(ldsH + abase + ks * 32);
            bf16x8 al = *reinterpret_cast<const bf16x8*>(ldsL + abase + ks * 32);
            acc = __builtin_amdgcn_mfma_f32_16x16x32_bf16(ah, wh[ks], acc, 0, 0, 0);
            acc = __builtin_amdgcn_mfma_f32_16x16x32_bf16(ah, wl[ks], acc, 0, 0, 0);
            acc = __builtin_amdgcn_mfma_f32_16x16x32_bf16(al, wh[ks], acc, 0, 0, 0);
        }
        // C/D layout: col = lane&15, row = (lane>>4)*4 + r   [m89-verified]
#pragma unroll
        for (int r = 0; r < 4; ++r) {
            int gr = row0 + rt * 16 + (lane >> 4) * 4 + r;
            if (gr < M) {
                float d = dinv[gr];
                float po = post ? d : 1.0f;
                float v = fmaxf(acc[r] * d + bb, 0.f) * po;
                C[(size_t)gr * 128 + col] = v;
            }
        }
    }
}

// ---------------- Final FC ----------------

__global__ void fc_kernel(const float* __restrict__ H3, const int* __restrict__ label,
                          const float* __restrict__ fcW, const float* __restrict__ fcb,
                          float* __restrict__ out, int P, int N) {
    int w = blockIdx.x * (blockDim.x >> 6) + (threadIdx.x >> 6);
    int lane = threadIdx.x & 63;
    if (w >= P) return;
    int l0 = label[2 * w], l1 = label[2 * w + 1] + N;
    float xl0 = H3[(size_t)l0 * 128 + lane];
    float xl1 = H3[(size_t)l0 * 128 + 64 + lane];
    float xr0 = H3[(size_t)l1 * 128 + lane];
    float xr1 = H3[(size_t)l1 * 128 + 64 + lane];
    float a0 = xl0 * fcW[lane * 2]             + xl1 * fcW[(64 + lane) * 2]
             + xr0 * fcW[(128 + lane) * 2]     + xr1 * fcW[(192 + lane) * 2];
    float a1 = xl0 * fcW[lane * 2 + 1]         + xl1 * fcW[(64 + lane) * 2 + 1]
             + xr0 * fcW[(128 + lane) * 2 + 1] + xr1 * fcW[(192 + lane) * 2 + 1];
#pragma unroll
    for (int o = 32; o; o >>= 1) {
        a0 += __shfl_xor(a0, o);
        a1 += __shfl_xor(a1, o);
    }
    if (lane == 0) {
        out[2 * w]     = fmaxf(a0 + fcb[0], 0.f);
        out[2 * w + 1] = fmaxf(a1 + fcb[1], 0.f);
    }
}

// ---------------- launch ----------------

extern "C" void kernel_launch(void* const* d_in, const int* in_sizes, int n_in,
                              void* d_out, int out_size, void* d_ws, size_t ws_size,
                              hipStream_t stream) {
    const float* x1   = (const float*)d_in[0];
    const int*   e1   = (const int*)d_in[1];
    const float* x2   = (const float*)d_in[2];
    const int*   e2   = (const int*)d_in[3];
    const int*   label= (const int*)d_in[4];
    const float* W0   = (const float*)d_in[5];
    const float* b0   = (const float*)d_in[6];
    const float* W1   = (const float*)d_in[7];
    const float* b1   = (const float*)d_in[8];
    const float* W2   = (const float*)d_in[9];
    const float* b2   = (const float*)d_in[10];
    const float* fcW  = (const float*)d_in[11];
    const float* fcb  = (const float*)d_in[12];
    float* out = (float*)d_out;

    const int N = in_sizes[0] / 64;
    const int E = in_sizes[1] / 2;
    const int P = in_sizes[4] / 2;
    const int NN = 2 * N;
    const int NB = (NN + 255) / 256;
    const int GB = (NN + 63) / 64;  // gemm blocks (BM=64)

    char* ws = (char*)d_ws;
    size_t off = 0;
    auto alloc = [&](size_t bytes) -> void* {
        void* p = ws + off;
        off += (bytes + 255) & ~(size_t)255;
        return p;
    };
    int*   cnt      = (int*)alloc((size_t)NN * 4);
    int*   rowptr   = (int*)alloc((size_t)(NN + 1) * 4);
    float* dinv     = (float*)alloc((size_t)NN * 4);
    int*   csr      = (int*)alloc((size_t)2 * E * 4);
    int*   blockSums= (int*)alloc((size_t)NB * 4);
    int*   blockOff = (int*)alloc((size_t)NB * 4);
    unsigned short* Shi = (unsigned short*)alloc((size_t)NN * 128 * 2);
    unsigned short* Slo = (unsigned short*)alloc((size_t)NN * 128 * 2);
    float* Xs       = (float*)alloc((size_t)NN * 128 * 4);
    unsigned short* W0h = (unsigned short*)alloc(64 * 128 * 2);
    unsigned short* W0l = (unsigned short*)alloc(64 * 128 * 2);
    unsigned short* W1h = (unsigned short*)alloc(128 * 128 * 2);
    unsigned short* W1l = (unsigned short*)alloc(128 * 128 * 2);
    unsigned short* W2h = (unsigned short*)alloc(128 * 128 * 2);
    unsigned short* W2l = (unsigned short*)alloc(128 * 128 * 2);

    prep_weights<<<3, 256, 0, stream>>>(W0, W1, W2, W0h, W0l, W1h, W1l, W2h, W2l);

    // CSR build (once, union graph)
    hipMemsetAsync(cnt, 0, (size_t)NN * 4, stream);
    histU_kernel<<<(2 * E + 255) / 256, 256, 0, stream>>>(e1 + E, e2 + E, cnt, E, N);
    block_reduce_kernel<<<NB, 256, 0, stream>>>(cnt, dinv, blockSums, NN);
    scan_sums_kernel<<<1, 1024, 0, stream>>>(blockSums, blockOff, NB, rowptr, NN);
    scan_write_kernel<<<NB, 256, 0, stream>>>(cnt, blockOff, rowptr, NN);
    placeU_kernel<<<(2 * E + 255) / 256, 256, 0, stream>>>(e1, e1 + E, e2, e2 + E,
                                                           rowptr, cnt, csr, E, N);
    // layer 0
    agg64U_kernel<<<(NN + 3) / 4, 256, 0, stream>>>(x1, x2, rowptr, csr, dinv, Shi, Slo, NN, N);
    gemm_mfma<64><<<GB, 512, 0, stream>>>(Shi, Slo, W0h, W0l, b0, dinv, 1, Xs, NN);
    // layer 1
    agg128_kernel<<<(NN + 3) / 4, 256, 0, stream>>>(Xs, rowptr, csr, Shi, Slo, NN);
    gemm_mfma<128><<<GB, 512, 0, stream>>>(Shi, Slo, W1h, W1l, b1, dinv, 1, Xs, NN);
    // layer 2 (no post-scale): H3 lands in Xs
    agg128_kernel<<<(NN + 3) / 4, 256, 0, stream>>>(Xs, rowptr, csr, Shi, Slo, NN);
    gemm_mfma<128><<<GB, 512, 0, stream>>>(Shi, Slo, W2h, W2l, b2, dinv, 0, Xs, NN);

    fc_kernel<<<(P + 3) / 4, 256, 0, stream>>>(Xs, label, fcW, fcb, out, P, N);
}

// Round 8
// 566.145 us; speedup vs baseline: 3.4620x; 1.1508x over previous
//
#include <hip/hip_runtime.h>
#include <math.h>

typedef __attribute__((ext_vector_type(8))) short bf16x8;
typedef __attribute__((ext_vector_type(4))) float f32x4;

__device__ inline unsigned short f2bf(float f) {
    unsigned int u = __float_as_uint(f);
    unsigned int r = u + 0x7fffu + ((u >> 16) & 1u);
    return (unsigned short)(r >> 16);
}
__device__ inline float bf2f(unsigned short b) {
    return __uint_as_float(((unsigned int)b) << 16);
}

// ---------------- CSR build (union graph: nodes [0,N)=g1, [N,2N)=g2) ----------------

__global__ void histU_kernel(const int* __restrict__ d1, const int* __restrict__ d2,
                             int* __restrict__ cnt, int E, int N) {
    int i = blockIdx.x * blockDim.x + threadIdx.x;
    if (i < E) atomicAdd(&cnt[d1[i]], 1);
    else if (i < 2 * E) atomicAdd(&cnt[N + d2[i - E]], 1);
}

__global__ __launch_bounds__(256) void block_reduce_kernel(const int* __restrict__ cnt,
                                                           float* __restrict__ dinv,
                                                           int* __restrict__ blockSums, int NN) {
    int i = blockIdx.x * 256 + threadIdx.x;
    int v = 0;
    if (i < NN) {
        v = cnt[i];
        dinv[i] = 1.0f / sqrtf((float)(v + 1));  // +1 self loop
    }
    int s = v;
#pragma unroll
    for (int o = 32; o; o >>= 1) s += __shfl_down(s, o);
    __shared__ int ws[4];
    if ((threadIdx.x & 63) == 0) ws[threadIdx.x >> 6] = s;
    __syncthreads();
    if (threadIdx.x == 0) blockSums[blockIdx.x] = ws[0] + ws[1] + ws[2] + ws[3];
}

__global__ __launch_bounds__(1024) void scan_sums_kernel(const int* __restrict__ blockSums,
                                                         int* __restrict__ blockOff, int nb,
                                                         int* __restrict__ rowptr, int NN) {
    __shared__ int sh[1024];
    int t = threadIdx.x;
    int v = (t < nb) ? blockSums[t] : 0;
    sh[t] = v;
    __syncthreads();
    for (int o = 1; o < 1024; o <<= 1) {
        int u = (t >= o) ? sh[t - o] : 0;
        __syncthreads();
        sh[t] += u;
        __syncthreads();
    }
    if (t < nb) blockOff[t] = sh[t] - v;
    if (t == 1023) rowptr[NN] = sh[1023];
}

__global__ __launch_bounds__(256) void scan_write_kernel(const int* __restrict__ cnt,
                                                         const int* __restrict__ blockOff,
                                                         int* __restrict__ rowptr, int NN) {
    __shared__ int sh[256];
    int i = blockIdx.x * 256 + threadIdx.x;
    int t = threadIdx.x;
    int v = (i < NN) ? cnt[i] : 0;
    sh[t] = v;
    __syncthreads();
    for (int o = 1; o < 256; o <<= 1) {
        int u = (t >= o) ? sh[t - o] : 0;
        __syncthreads();
        sh[t] += u;
        __syncthreads();
    }
    if (i < NN) rowptr[i] = blockOff[blockIdx.x] + sh[t] - v;
}

__global__ void placeU_kernel(const int* __restrict__ s1, const int* __restrict__ d1,
                              const int* __restrict__ s2, const int* __restrict__ d2,
                              const int* __restrict__ rowptr, int* __restrict__ cnt,
                              int* __restrict__ csr, int E, int N) {
    int i = blockIdx.x * blockDim.x + threadIdx.x;
    int s, d;
    if (i < E)          { s = s1[i];         d = d1[i]; }
    else if (i < 2 * E) { s = s2[i - E] + N; d = d2[i - E] + N; }
    else return;
    int p = atomicSub(&cnt[d], 1);  // old count, 1..deg; drains cnt to 0
    csr[rowptr[d] + p - 1] = s;
}

// ---------------- Weight prep: W[K][128] f32 -> WhT/WlT [128][K] bf16 ----------------

__global__ void prep_weights(const float* __restrict__ W0, const float* __restrict__ W1,
                             const float* __restrict__ W2,
                             unsigned short* __restrict__ W0h, unsigned short* __restrict__ W0l,
                             unsigned short* __restrict__ W1h, unsigned short* __restrict__ W1l,
                             unsigned short* __restrict__ W2h, unsigned short* __restrict__ W2l) {
    const float* W; unsigned short *Wh, *Wl; int K;
    if (blockIdx.x == 0)      { W = W0; Wh = W0h; Wl = W0l; K = 64; }
    else if (blockIdx.x == 1) { W = W1; Wh = W1h; Wl = W1l; K = 128; }
    else                      { W = W2; Wh = W2h; Wl = W2l; K = 128; }
    for (int i = threadIdx.x; i < K * 128; i += 256) {
        int k = i >> 7, c = i & 127;
        float v = W[i];
        unsigned short h = f2bf(v);
        unsigned short l = f2bf(v - bf2f(h));
        Wh[c * K + k] = h;
        Wl[c * K + k] = l;
    }
}

// ---- Prescale: X0[i] = dinv[i] * x(i), unified [NN][64] f32 (coalesced) ----

__global__ void prescale_kernel(const float* __restrict__ x1, const float* __restrict__ x2,
                                const float* __restrict__ dinv, float* __restrict__ X0, int NN,
                                int N) {
    int i = blockIdx.x * blockDim.x + threadIdx.x;  // over NN*16 float4
    if (i >= NN * 16) return;
    int r = i >> 4;
    const float4* src = (r < N) ? (const float4*)(x1) + i
                                : (const float4*)(x2) + (i - N * 16);
    float4 v = *src;
    float d = dinv[r];
    v.x *= d; v.y *= d; v.z *= d; v.w *= d;
    reinterpret_cast<float4*>(X0)[i] = v;
}

// ------- Layer-0 aggregation from prescaled X0: pure gather+add; split-bf16 out -------

__global__ void agg64_kernel(const float* __restrict__ X0, const int* __restrict__ rowptr,
                             const int* __restrict__ csr,
                             unsigned short* __restrict__ Shi, unsigned short* __restrict__ Slo,
                             int NN) {
    int w = blockIdx.x * (blockDim.x >> 6) + (threadIdx.x >> 6);
    int lane = threadIdx.x & 63;
    if (w >= NN) return;
    int beg = rowptr[w], end = rowptr[w + 1];
    float acc = X0[(size_t)w * 64 + lane];  // self (prescaled)
    int e = beg;
    int full_end = beg + ((end - beg) & ~7);
    for (; e < full_end; e += 8) {
        int s0 = csr[e], s1 = csr[e + 1], s2 = csr[e + 2], s3 = csr[e + 3];
        int s4 = csr[e + 4], s5 = csr[e + 5], s6 = csr[e + 6], s7 = csr[e + 7];
        float v0 = X0[(size_t)s0 * 64 + lane];
        float v1 = X0[(size_t)s1 * 64 + lane];
        float v2 = X0[(size_t)s2 * 64 + lane];
        float v3 = X0[(size_t)s3 * 64 + lane];
        float v4 = X0[(size_t)s4 * 64 + lane];
        float v5 = X0[(size_t)s5 * 64 + lane];
        float v6 = X0[(size_t)s6 * 64 + lane];
        float v7 = X0[(size_t)s7 * 64 + lane];
        acc += ((v0 + v1) + (v2 + v3)) + ((v4 + v5) + (v6 + v7));
    }
    if (e < end) {  // masked batch keeps up to 7 gathers in flight
#pragma unroll
        for (int j = 0; j < 7; ++j) {
            int a = e + j;
            bool vld = a < end;
            int s = csr[vld ? a : beg];
            float m = vld ? 1.f : 0.f;
            acc += m * X0[(size_t)s * 64 + lane];
        }
    }
    unsigned short h = f2bf(acc);
    Shi[(size_t)w * 64 + lane] = h;
    Slo[(size_t)w * 64 + lane] = f2bf(acc - bf2f(h));
}

// ------- Layers 1-2 aggregation: input f32 (pre-scaled), output split bf16 -------

__global__ void agg128_kernel(const float* __restrict__ Xf, const int* __restrict__ rowptr,
                              const int* __restrict__ csr,
                              unsigned short* __restrict__ Shi, unsigned short* __restrict__ Slo,
                              int NN) {
    int w = blockIdx.x * (blockDim.x >> 6) + (threadIdx.x >> 6);
    int lane = threadIdx.x & 63;
    if (w >= NN) return;
    const float2* X = (const float2*)Xf;
    int beg = rowptr[w], end = rowptr[w + 1];
    float2 self = X[(size_t)w * 64 + lane];
    float ax = self.x, ay = self.y;
    int e = beg;
    int full_end = beg + ((end - beg) & ~7);
    for (; e < full_end; e += 8) {
        int s0 = csr[e], s1 = csr[e + 1], s2 = csr[e + 2], s3 = csr[e + 3];
        int s4 = csr[e + 4], s5 = csr[e + 5], s6 = csr[e + 6], s7 = csr[e + 7];
        float2 v0 = X[(size_t)s0 * 64 + lane];
        float2 v1 = X[(size_t)s1 * 64 + lane];
        float2 v2 = X[(size_t)s2 * 64 + lane];
        float2 v3 = X[(size_t)s3 * 64 + lane];
        float2 v4 = X[(size_t)s4 * 64 + lane];
        float2 v5 = X[(size_t)s5 * 64 + lane];
        float2 v6 = X[(size_t)s6 * 64 + lane];
        float2 v7 = X[(size_t)s7 * 64 + lane];
        ax += ((v0.x + v1.x) + (v2.x + v3.x)) + ((v4.x + v5.x) + (v6.x + v7.x));
        ay += ((v0.y + v1.y) + (v2.y + v3.y)) + ((v4.y + v5.y) + (v6.y + v7.y));
    }
    if (e < end) {
#pragma unroll
        for (int j = 0; j < 7; ++j) {
            int a = e + j;
            bool vld = a < end;
            int s = csr[vld ? a : beg];
            float m = vld ? 1.f : 0.f;
            float2 v = X[(size_t)s * 64 + lane];
            ax += m * v.x; ay += m * v.y;
        }
    }
    unsigned short hx = f2bf(ax), hy = f2bf(ay);
    ushort2 H; H.x = hx; H.y = hy;
    ushort2 L; L.x = f2bf(ax - bf2f(hx)); L.y = f2bf(ay - bf2f(hy));
    *reinterpret_cast<ushort2*>(Shi + (size_t)w * 128 + 2 * lane) = H;
    *reinterpret_cast<ushort2*>(Slo + (size_t)w * 128 + 2 * lane) = L;
}

// ---- MFMA GEMM: C[r] = po(r)*relu(dinv[r]*(A@W)[r] + bias), A = Ah+Al (split bf16) ----
// BM=64, 512 threads = 8 waves; wave w owns cols [16w,16w+16). LDS 35KB -> 4 blocks/CU.

template <int K>
__global__ __launch_bounds__(512) void gemm_mfma(const unsigned short* __restrict__ Ah,
                                                 const unsigned short* __restrict__ Al,
                                                 const unsigned short* __restrict__ WhT,
                                                 const unsigned short* __restrict__ WlT,
                                                 const float* __restrict__ bias,
                                                 const float* __restrict__ dinv, int post,
                                                 float* __restrict__ C, int M) {
    const int LDA = K + 8;
    __shared__ unsigned short ldsH[64 * LDA];
    __shared__ unsigned short ldsL[64 * LDA];

    int t = threadIdx.x;
    int lane = t & 63, wid = t >> 6;
    int c16 = lane & 15, kq = (lane >> 4) * 8;
    int row0 = blockIdx.x * 64;
    int col = wid * 16 + c16;

    bf16x8 wh[K / 32], wl[K / 32];
#pragma unroll
    for (int ks = 0; ks < K / 32; ++ks) {
        wh[ks] = *reinterpret_cast<const bf16x8*>(WhT + (size_t)col * K + ks * 32 + kq);
        wl[ks] = *reinterpret_cast<const bf16x8*>(WlT + (size_t)col * K + ks * 32 + kq);
    }

    const int CH = 64 * (K / 8);
    for (int c = t; c < CH; c += 512) {
        int row = c / (K / 8), kb = c % (K / 8);
        int gr = row0 + row; if (gr >= M) gr = M - 1;
        *reinterpret_cast<bf16x8*>(&ldsH[row * LDA + kb * 8]) =
            *reinterpret_cast<const bf16x8*>(Ah + (size_t)gr * K + kb * 8);
        *reinterpret_cast<bf16x8*>(&ldsL[row * LDA + kb * 8]) =
            *reinterpret_cast<const bf16x8*>(Al + (size_t)gr * K + kb * 8);
    }
    __syncthreads();

    float bb = bias[col];
#pragma unroll
    for (int rt = 0; rt < 4; ++rt) {
        f32x4 acc = {0.f, 0.f, 0.f, 0.f};
        int abase = (rt * 16 + c16) * LDA + kq;
#pragma unroll
        for (int ks = 0; ks < K / 32; ++ks) {
            bf16x8 ah = *reinterpret_cast<const bf16x8*>(ldsH + abase + ks * 32);
            bf16x8 al = *reinterpret_cast<const bf16x8*>(ldsL + abase + ks * 32);
            acc = __builtin_amdgcn_mfma_f32_16x16x32_bf16(ah, wh[ks], acc, 0, 0, 0);
            acc = __builtin_amdgcn_mfma_f32_16x16x32_bf16(ah, wl[ks], acc, 0, 0, 0);
            acc = __builtin_amdgcn_mfma_f32_16x16x32_bf16(al, wh[ks], acc, 0, 0, 0);
        }
        // C/D layout: col = lane&15, row = (lane>>4)*4 + r   [m89-verified]
#pragma unroll
        for (int r = 0; r < 4; ++r) {
            int gr = row0 + rt * 16 + (lane >> 4) * 4 + r;
            if (gr < M) {
                float d = dinv[gr];
                float po = post ? d : 1.0f;
                float v = fmaxf(acc[r] * d + bb, 0.f) * po;
                C[(size_t)gr * 128 + col] = v;
            }
        }
    }
}

// ---------------- Final FC ----------------

__global__ void fc_kernel(const float* __restrict__ H3, const int* __restrict__ label,
                          const float* __restrict__ fcW, const float* __restrict__ fcb,
                          float* __restrict__ out, int P, int N) {
    int w = blockIdx.x * (blockDim.x >> 6) + (threadIdx.x >> 6);
    int lane = threadIdx.x & 63;
    if (w >= P) return;
    int l0 = label[2 * w], l1 = label[2 * w + 1] + N;
    float xl0 = H3[(size_t)l0 * 128 + lane];
    float xl1 = H3[(size_t)l0 * 128 + 64 + lane];
    float xr0 = H3[(size_t)l1 * 128 + lane];
    float xr1 = H3[(size_t)l1 * 128 + 64 + lane];
    float a0 = xl0 * fcW[lane * 2]             + xl1 * fcW[(64 + lane) * 2]
             + xr0 * fcW[(128 + lane) * 2]     + xr1 * fcW[(192 + lane) * 2];
    float a1 = xl0 * fcW[lane * 2 + 1]         + xl1 * fcW[(64 + lane) * 2 + 1]
             + xr0 * fcW[(128 + lane) * 2 + 1] + xr1 * fcW[(192 + lane) * 2 + 1];
#pragma unroll
    for (int o = 32; o; o >>= 1) {
        a0 += __shfl_xor(a0, o);
        a1 += __shfl_xor(a1, o);
    }
    if (lane == 0) {
        out[2 * w]     = fmaxf(a0 + fcb[0], 0.f);
        out[2 * w + 1] = fmaxf(a1 + fcb[1], 0.f);
    }
}

// ---------------- launch ----------------

extern "C" void kernel_launch(void* const* d_in, const int* in_sizes, int n_in,
                              void* d_out, int out_size, void* d_ws, size_t ws_size,
                              hipStream_t stream) {
    const float* x1   = (const float*)d_in[0];
    const int*   e1   = (const int*)d_in[1];
    const float* x2   = (const float*)d_in[2];
    const int*   e2   = (const int*)d_in[3];
    const int*   label= (const int*)d_in[4];
    const float* W0   = (const float*)d_in[5];
    const float* b0   = (const float*)d_in[6];
    const float* W1   = (const float*)d_in[7];
    const float* b1   = (const float*)d_in[8];
    const float* W2   = (const float*)d_in[9];
    const float* b2   = (const float*)d_in[10];
    const float* fcW  = (const float*)d_in[11];
    const float* fcb  = (const float*)d_in[12];
    float* out = (float*)d_out;

    const int N = in_sizes[0] / 64;
    const int E = in_sizes[1] / 2;
    const int P = in_sizes[4] / 2;
    const int NN = 2 * N;
    const int NB = (NN + 255) / 256;
    const int GB = (NN + 63) / 64;  // gemm blocks (BM=64)

    char* ws = (char*)d_ws;
    size_t off = 0;
    auto alloc = [&](size_t bytes) -> void* {
        void* p = ws + off;
        off += (bytes + 255) & ~(size_t)255;
        return p;
    };
    int*   cnt      = (int*)alloc((size_t)NN * 4);
    int*   rowptr   = (int*)alloc((size_t)(NN + 1) * 4);
    float* dinv     = (float*)alloc((size_t)NN * 4);
    int*   csr      = (int*)alloc((size_t)2 * E * 4);
    int*   blockSums= (int*)alloc((size_t)NB * 4);
    int*   blockOff = (int*)alloc((size_t)NB * 4);
    unsigned short* Shi = (unsigned short*)alloc((size_t)NN * 128 * 2);
    unsigned short* Slo = (unsigned short*)alloc((size_t)NN * 128 * 2);
    float* Xs       = (float*)alloc((size_t)NN * 128 * 4);  // X0 (layer0, [NN][64]) then H, then H3
    unsigned short* W0h = (unsigned short*)alloc(64 * 128 * 2);
    unsigned short* W0l = (unsigned short*)alloc(64 * 128 * 2);
    unsigned short* W1h = (unsigned short*)alloc(128 * 128 * 2);
    unsigned short* W1l = (unsigned short*)alloc(128 * 128 * 2);
    unsigned short* W2h = (unsigned short*)alloc(128 * 128 * 2);
    unsigned short* W2l = (unsigned short*)alloc(128 * 128 * 2);

    prep_weights<<<3, 256, 0, stream>>>(W0, W1, W2, W0h, W0l, W1h, W1l, W2h, W2l);

    // CSR build (once, union graph)
    hipMemsetAsync(cnt, 0, (size_t)NN * 4, stream);
    histU_kernel<<<(2 * E + 255) / 256, 256, 0, stream>>>(e1 + E, e2 + E, cnt, E, N);
    block_reduce_kernel<<<NB, 256, 0, stream>>>(cnt, dinv, blockSums, NN);
    scan_sums_kernel<<<1, 1024, 0, stream>>>(blockSums, blockOff, NB, rowptr, NN);
    scan_write_kernel<<<NB, 256, 0, stream>>>(cnt, blockOff, rowptr, NN);
    placeU_kernel<<<(2 * E + 255) / 256, 256, 0, stream>>>(e1, e1 + E, e2, e2 + E,
                                                           rowptr, cnt, csr, E, N);
    // layer 0: prescale into unified X0, pure-gather agg, GEMM 64->128
    prescale_kernel<<<(NN * 16 + 255) / 256, 256, 0, stream>>>(x1, x2, dinv, Xs, NN, N);
    agg64_kernel<<<(NN + 3) / 4, 256, 0, stream>>>(Xs, rowptr, csr, Shi, Slo, NN);
    gemm_mfma<64><<<GB, 512, 0, stream>>>(Shi, Slo, W0h, W0l, b0, dinv, 1, Xs, NN);
    // layer 1
    agg128_kernel<<<(NN + 3) / 4, 256, 0, stream>>>(Xs, rowptr, csr, Shi, Slo, NN);
    gemm_mfma<128><<<GB, 512, 0, stream>>>(Shi, Slo, W1h, W1l, b1, dinv, 1, Xs, NN);
    // layer 2 (no post-scale): H3 lands in Xs
    agg128_kernel<<<(NN + 3) / 4, 256, 0, stream>>>(Xs, rowptr, csr, Shi, Slo, NN);
    gemm_mfma<128><<<GB, 512, 0, stream>>>(Shi, Slo, W2h, W2l, b2, dinv, 0, Xs, NN);

    fc_kernel<<<(P + 3) / 4, 256, 0, stream>>>(Xs, label, fcW, fcb, out, P, N);
}

// Round 9
// 561.012 us; speedup vs baseline: 3.4937x; 1.0091x over previous
//
#include <hip/hip_runtime.h>
#include <math.h>

typedef __attribute__((ext_vector_type(8))) short bf16x8;
typedef __attribute__((ext_vector_type(4))) float f32x4;

__device__ inline unsigned short f2bf(float f) {
    unsigned int u = __float_as_uint(f);
    unsigned int r = u + 0x7fffu + ((u >> 16) & 1u);
    return (unsigned short)(r >> 16);
}
__device__ inline float bf2f(unsigned short b) {
    return __uint_as_float(((unsigned int)b) << 16);
}

// ---------------- CSR build (union graph: nodes [0,N)=g1, [N,2N)=g2) ----------------

__global__ void histU_kernel(const int* __restrict__ d1, const int* __restrict__ d2,
                             int* __restrict__ cnt, int E, int N) {
    int i = blockIdx.x * blockDim.x + threadIdx.x;
    if (i < E) atomicAdd(&cnt[d1[i]], 1);
    else if (i < 2 * E) atomicAdd(&cnt[N + d2[i - E]], 1);
}

__global__ __launch_bounds__(256) void block_reduce_kernel(const int* __restrict__ cnt,
                                                           float* __restrict__ dinv,
                                                           int* __restrict__ blockSums, int NN) {
    int i = blockIdx.x * 256 + threadIdx.x;
    int v = 0;
    if (i < NN) {
        v = cnt[i];
        dinv[i] = 1.0f / sqrtf((float)(v + 1));  // +1 self loop
    }
    int s = v;
#pragma unroll
    for (int o = 32; o; o >>= 1) s += __shfl_down(s, o);
    __shared__ int ws[4];
    if ((threadIdx.x & 63) == 0) ws[threadIdx.x >> 6] = s;
    __syncthreads();
    if (threadIdx.x == 0) blockSums[blockIdx.x] = ws[0] + ws[1] + ws[2] + ws[3];
}

__global__ __launch_bounds__(1024) void scan_sums_kernel(const int* __restrict__ blockSums,
                                                         int* __restrict__ blockOff, int nb,
                                                         int* __restrict__ rowptr, int NN) {
    __shared__ int sh[1024];
    int t = threadIdx.x;
    int v = (t < nb) ? blockSums[t] : 0;
    sh[t] = v;
    __syncthreads();
    for (int o = 1; o < 1024; o <<= 1) {
        int u = (t >= o) ? sh[t - o] : 0;
        __syncthreads();
        sh[t] += u;
        __syncthreads();
    }
    if (t < nb) blockOff[t] = sh[t] - v;
    if (t == 1023) rowptr[NN] = sh[1023];
}

__global__ __launch_bounds__(256) void scan_write_kernel(const int* __restrict__ cnt,
                                                         const int* __restrict__ blockOff,
                                                         int* __restrict__ rowptr, int NN) {
    __shared__ int sh[256];
    int i = blockIdx.x * 256 + threadIdx.x;
    int t = threadIdx.x;
    int v = (i < NN) ? cnt[i] : 0;
    sh[t] = v;
    __syncthreads();
    for (int o = 1; o < 256; o <<= 1) {
        int u = (t >= o) ? sh[t - o] : 0;
        __syncthreads();
        sh[t] += u;
        __syncthreads();
    }
    if (i < NN) rowptr[i] = blockOff[blockIdx.x] + sh[t] - v;
}

__global__ void placeU_kernel(const int* __restrict__ s1, const int* __restrict__ d1,
                              const int* __restrict__ s2, const int* __restrict__ d2,
                              const int* __restrict__ rowptr, int* __restrict__ cnt,
                              int* __restrict__ csr, int E, int N) {
    int i = blockIdx.x * blockDim.x + threadIdx.x;
    int s, d;
    if (i < E)          { s = s1[i];         d = d1[i]; }
    else if (i < 2 * E) { s = s2[i - E] + N; d = d2[i - E] + N; }
    else return;
    int p = atomicSub(&cnt[d], 1);  // old count, 1..deg; drains cnt to 0
    csr[rowptr[d] + p - 1] = s;
}

// ---------------- Weight prep: W[K][128] f32 -> WhT/WlT [128][K] bf16 ----------------

__global__ void prep_weights(const float* __restrict__ W0, const float* __restrict__ W1,
                             const float* __restrict__ W2,
                             unsigned short* __restrict__ W0h, unsigned short* __restrict__ W0l,
                             unsigned short* __restrict__ W1h, unsigned short* __restrict__ W1l,
                             unsigned short* __restrict__ W2h, unsigned short* __restrict__ W2l) {
    const float* W; unsigned short *Wh, *Wl; int K;
    if (blockIdx.x == 0)      { W = W0; Wh = W0h; Wl = W0l; K = 64; }
    else if (blockIdx.x == 1) { W = W1; Wh = W1h; Wl = W1l; K = 128; }
    else                      { W = W2; Wh = W2h; Wl = W2l; K = 128; }
    for (int i = threadIdx.x; i < K * 128; i += 256) {
        int k = i >> 7, c = i & 127;
        float v = W[i];
        unsigned short h = f2bf(v);
        unsigned short l = f2bf(v - bf2f(h));
        Wh[c * K + k] = h;
        Wl[c * K + k] = l;
    }
}

// ---- Prescale: X0[i] = dinv[i] * x(i), unified [NN][64] f32 (coalesced) ----

__global__ void prescale_kernel(const float* __restrict__ x1, const float* __restrict__ x2,
                                const float* __restrict__ dinv, float* __restrict__ X0, int NN,
                                int N) {
    int i = blockIdx.x * blockDim.x + threadIdx.x;  // over NN*16 float4
    if (i >= NN * 16) return;
    int r = i >> 4;
    const float4* src = (r < N) ? (const float4*)(x1) + i
                                : (const float4*)(x2) + (i - N * 16);
    float4 v = *src;
    float d = dinv[r];
    v.x *= d; v.y *= d; v.z *= d; v.w *= d;
    reinterpret_cast<float4*>(X0)[i] = v;
}

// ---- Fused agg + MFMA GEMM. Block = 64 output rows, 512 threads = 8 waves.
// Phase 1: wave w aggregates rows [w*8, w*8+8) (proven 8-deep gather loop),
//          writes split-bf16 directly to the GEMM LDS tiles.
// Phase 2: proven MFMA GEMM from LDS; wave w owns cols [16w, 16w+16).
// C[r] = po(r)*relu(dinv[r]*(Agg@W)[r] + bias), po = dinv[r] if post else 1.

template <int K>
__global__ __launch_bounds__(512) void fused_agg_gemm(
    const float* __restrict__ X, const int* __restrict__ rowptr,
    const int* __restrict__ csr,
    const unsigned short* __restrict__ WhT, const unsigned short* __restrict__ WlT,
    const float* __restrict__ bias, const float* __restrict__ dinv, int post,
    float* __restrict__ C, int M) {
    const int LDA = K + 8;
    __shared__ unsigned short ldsH[64 * LDA];
    __shared__ unsigned short ldsL[64 * LDA];

    int t = threadIdx.x;
    int lane = t & 63, wid = t >> 6;
    int row0 = blockIdx.x * 64;

    // ---------- phase 1: aggregation (8 nodes per wave) ----------
    for (int rr = 0; rr < 8; ++rr) {
        int row = wid * 8 + rr;
        int g = row0 + row; if (g >= M) g = M - 1;
        int beg = rowptr[g], end = rowptr[g + 1];
        if constexpr (K == 128) {
            const float2* X2 = (const float2*)X;
            float2 self = X2[(size_t)g * 64 + lane];
            float ax = self.x, ay = self.y;
            int e = beg;
            int full_end = beg + ((end - beg) & ~7);
            for (; e < full_end; e += 8) {
                int s0 = csr[e], s1 = csr[e + 1], s2 = csr[e + 2], s3 = csr[e + 3];
                int s4 = csr[e + 4], s5 = csr[e + 5], s6 = csr[e + 6], s7 = csr[e + 7];
                float2 v0 = X2[(size_t)s0 * 64 + lane];
                float2 v1 = X2[(size_t)s1 * 64 + lane];
                float2 v2 = X2[(size_t)s2 * 64 + lane];
                float2 v3 = X2[(size_t)s3 * 64 + lane];
                float2 v4 = X2[(size_t)s4 * 64 + lane];
                float2 v5 = X2[(size_t)s5 * 64 + lane];
                float2 v6 = X2[(size_t)s6 * 64 + lane];
                float2 v7 = X2[(size_t)s7 * 64 + lane];
                ax += ((v0.x + v1.x) + (v2.x + v3.x)) + ((v4.x + v5.x) + (v6.x + v7.x));
                ay += ((v0.y + v1.y) + (v2.y + v3.y)) + ((v4.y + v5.y) + (v6.y + v7.y));
            }
            if (e < end) {
#pragma unroll
                for (int j = 0; j < 7; ++j) {
                    int a = e + j;
                    bool vld = a < end;
                    int s = csr[vld ? a : beg];
                    float m = vld ? 1.f : 0.f;
                    float2 v = X2[(size_t)s * 64 + lane];
                    ax += m * v.x; ay += m * v.y;
                }
            }
            unsigned short hx = f2bf(ax), hy = f2bf(ay);
            ushort2 H; H.x = hx; H.y = hy;
            ushort2 L; L.x = f2bf(ax - bf2f(hx)); L.y = f2bf(ay - bf2f(hy));
            *reinterpret_cast<ushort2*>(&ldsH[row * LDA + 2 * lane]) = H;
            *reinterpret_cast<ushort2*>(&ldsL[row * LDA + 2 * lane]) = L;
        } else {
            float acc = X[(size_t)g * 64 + lane];
            int e = beg;
            int full_end = beg + ((end - beg) & ~7);
            for (; e < full_end; e += 8) {
                int s0 = csr[e], s1 = csr[e + 1], s2 = csr[e + 2], s3 = csr[e + 3];
                int s4 = csr[e + 4], s5 = csr[e + 5], s6 = csr[e + 6], s7 = csr[e + 7];
                float v0 = X[(size_t)s0 * 64 + lane];
                float v1 = X[(size_t)s1 * 64 + lane];
                float v2 = X[(size_t)s2 * 64 + lane];
                float v3 = X[(size_t)s3 * 64 + lane];
                float v4 = X[(size_t)s4 * 64 + lane];
                float v5 = X[(size_t)s5 * 64 + lane];
                float v6 = X[(size_t)s6 * 64 + lane];
                float v7 = X[(size_t)s7 * 64 + lane];
                acc += ((v0 + v1) + (v2 + v3)) + ((v4 + v5) + (v6 + v7));
            }
            if (e < end) {
#pragma unroll
                for (int j = 0; j < 7; ++j) {
                    int a = e + j;
                    bool vld = a < end;
                    int s = csr[vld ? a : beg];
                    float m = vld ? 1.f : 0.f;
                    acc += m * X[(size_t)s * 64 + lane];
                }
            }
            unsigned short h = f2bf(acc);
            ldsH[row * LDA + lane] = h;
            ldsL[row * LDA + lane] = f2bf(acc - bf2f(h));
        }
    }
    __syncthreads();

    // ---------- phase 2: MFMA GEMM from LDS ----------
    int c16 = lane & 15, kq = (lane >> 4) * 8;
    int col = wid * 16 + c16;

    bf16x8 wh[K / 32], wl[K / 32];
#pragma unroll
    for (int ks = 0; ks < K / 32; ++ks) {
        wh[ks] = *reinterpret_cast<const bf16x8*>(WhT + (size_t)col * K + ks * 32 + kq);
        wl[ks] = *reinterpret_cast<const bf16x8*>(WlT + (size_t)col * K + ks * 32 + kq);
    }
    float bb = bias[col];

#pragma unroll
    for (int rt = 0; rt < 4; ++rt) {
        f32x4 acc = {0.f, 0.f, 0.f, 0.f};
        int abase = (rt * 16 + c16) * LDA + kq;
#pragma unroll
        for (int ks = 0; ks < K / 32; ++ks) {
            bf16x8 ah = *reinterpret_cast<const bf16x8*>(ldsH + abase + ks * 32);
            bf16x8 al = *reinterpret_cast<const bf16x8*>(ldsL + abase + ks * 32);
            acc = __builtin_amdgcn_mfma_f32_16x16x32_bf16(ah, wh[ks], acc, 0, 0, 0);
            acc = __builtin_amdgcn_mfma_f32_16x16x32_bf16(ah, wl[ks], acc, 0, 0, 0);
            acc = __builtin_amdgcn_mfma_f32_16x16x32_bf16(al, wh[ks], acc, 0, 0, 0);
        }
        // C/D layout: col = lane&15, row = (lane>>4)*4 + r   [m89-verified]
#pragma unroll
        for (int r = 0; r < 4; ++r) {
            int gr = row0 + rt * 16 + (lane >> 4) * 4 + r;
            if (gr < M) {
                float d = dinv[gr];
                float po = post ? d : 1.0f;
                float v = fmaxf(acc[r] * d + bb, 0.f) * po;
                C[(size_t)gr * 128 + col] = v;
            }
        }
    }
}

// ---------------- Final FC ----------------

__global__ void fc_kernel(const float* __restrict__ H3, const int* __restrict__ label,
                          const float* __restrict__ fcW, const float* __restrict__ fcb,
                          float* __restrict__ out, int P, int N) {
    int w = blockIdx.x * (blockDim.x >> 6) + (threadIdx.x >> 6);
    int lane = threadIdx.x & 63;
    if (w >= P) return;
    int l0 = label[2 * w], l1 = label[2 * w + 1] + N;
    float xl0 = H3[(size_t)l0 * 128 + lane];
    float xl1 = H3[(size_t)l0 * 128 + 64 + lane];
    float xr0 = H3[(size_t)l1 * 128 + lane];
    float xr1 = H3[(size_t)l1 * 128 + 64 + lane];
    float a0 = xl0 * fcW[lane * 2]             + xl1 * fcW[(64 + lane) * 2]
             + xr0 * fcW[(128 + lane) * 2]     + xr1 * fcW[(192 + lane) * 2];
    float a1 = xl0 * fcW[lane * 2 + 1]         + xl1 * fcW[(64 + lane) * 2 + 1]
             + xr0 * fcW[(128 + lane) * 2 + 1] + xr1 * fcW[(192 + lane) * 2 + 1];
#pragma unroll
    for (int o = 32; o; o >>= 1) {
        a0 += __shfl_xor(a0, o);
        a1 += __shfl_xor(a1, o);
    }
    if (lane == 0) {
        out[2 * w]     = fmaxf(a0 + fcb[0], 0.f);
        out[2 * w + 1] = fmaxf(a1 + fcb[1], 0.f);
    }
}

// ---------------- launch ----------------

extern "C" void kernel_launch(void* const* d_in, const int* in_sizes, int n_in,
                              void* d_out, int out_size, void* d_ws, size_t ws_size,
                              hipStream_t stream) {
    const float* x1   = (const float*)d_in[0];
    const int*   e1   = (const int*)d_in[1];
    const float* x2   = (const float*)d_in[2];
    const int*   e2   = (const int*)d_in[3];
    const int*   label= (const int*)d_in[4];
    const float* W0   = (const float*)d_in[5];
    const float* b0   = (const float*)d_in[6];
    const float* W1   = (const float*)d_in[7];
    const float* b1   = (const float*)d_in[8];
    const float* W2   = (const float*)d_in[9];
    const float* b2   = (const float*)d_in[10];
    const float* fcW  = (const float*)d_in[11];
    const float* fcb  = (const float*)d_in[12];
    float* out = (float*)d_out;

    const int N = in_sizes[0] / 64;
    const int E = in_sizes[1] / 2;
    const int P = in_sizes[4] / 2;
    const int NN = 2 * N;
    const int NB = (NN + 255) / 256;
    const int GB = (NN + 63) / 64;  // fused blocks (64 rows each)

    char* ws = (char*)d_ws;
    size_t off = 0;
    auto alloc = [&](size_t bytes) -> void* {
        void* p = ws + off;
        off += (bytes + 255) & ~(size_t)255;
        return p;
    };
    int*   cnt      = (int*)alloc((size_t)NN * 4);
    int*   rowptr   = (int*)alloc((size_t)(NN + 1) * 4);
    float* dinv     = (float*)alloc((size_t)NN * 4);
    int*   csr      = (int*)alloc((size_t)2 * E * 4);
    int*   blockSums= (int*)alloc((size_t)NB * 4);
    int*   blockOff = (int*)alloc((size_t)NB * 4);
    float* bufA     = (float*)alloc((size_t)NN * 128 * 4);  // X0 ([NN][64]) then H2
    float* bufB     = (float*)alloc((size_t)NN * 128 * 4);  // H1 then H3
    unsigned short* W0h = (unsigned short*)alloc(64 * 128 * 2);
    unsigned short* W0l = (unsigned short*)alloc(64 * 128 * 2);
    unsigned short* W1h = (unsigned short*)alloc(128 * 128 * 2);
    unsigned short* W1l = (unsigned short*)alloc(128 * 128 * 2);
    unsigned short* W2h = (unsigned short*)alloc(128 * 128 * 2);
    unsigned short* W2l = (unsigned short*)alloc(128 * 128 * 2);

    prep_weights<<<3, 256, 0, stream>>>(W0, W1, W2, W0h, W0l, W1h, W1l, W2h, W2l);

    // CSR build (once, union graph)
    hipMemsetAsync(cnt, 0, (size_t)NN * 4, stream);
    histU_kernel<<<(2 * E + 255) / 256, 256, 0, stream>>>(e1 + E, e2 + E, cnt, E, N);
    block_reduce_kernel<<<NB, 256, 0, stream>>>(cnt, dinv, blockSums, NN);
    scan_sums_kernel<<<1, 1024, 0, stream>>>(blockSums, blockOff, NB, rowptr, NN);
    scan_write_kernel<<<NB, 256, 0, stream>>>(cnt, blockOff, rowptr, NN);
    placeU_kernel<<<(2 * E + 255) / 256, 256, 0, stream>>>(e1, e1 + E, e2, e2 + E,
                                                           rowptr, cnt, csr, E, N);
    // layer 0: prescale into X0 (bufA), fused agg+GEMM 64->128 into bufB
    prescale_kernel<<<(NN * 16 + 255) / 256, 256, 0, stream>>>(x1, x2, dinv, bufA, NN, N);
    fused_agg_gemm<64><<<GB, 512, 0, stream>>>(bufA, rowptr, csr, W0h, W0l, b0, dinv, 1,
                                               bufB, NN);
    // layer 1: bufB -> bufA
    fused_agg_gemm<128><<<GB, 512, 0, stream>>>(bufB, rowptr, csr, W1h, W1l, b1, dinv, 1,
                                                bufA, NN);
    // layer 2 (no post-scale): bufA -> bufB (H3)
    fused_agg_gemm<128><<<GB, 512, 0, stream>>>(bufA, rowptr, csr, W2h, W2l, b2, dinv, 0,
                                                bufB, NN);

    fc_kernel<<<(P + 3) / 4, 256, 0, stream>>>(bufB, label, fcW, fcb, out, P, N);
}

// Round 10
// 559.108 us; speedup vs baseline: 3.5056x; 1.0034x over previous
//
#include <hip/hip_runtime.h>
#include <math.h>

typedef __attribute__((ext_vector_type(8))) short bf16x8;
typedef __attribute__((ext_vector_type(4))) float f32x4;

__device__ inline unsigned short f2bf(float f) {
    unsigned int u = __float_as_uint(f);
    unsigned int r = u + 0x7fffu + ((u >> 16) & 1u);
    return (unsigned short)(r >> 16);
}
__device__ inline float bf2f(unsigned short b) {
    return __uint_as_float(((unsigned int)b) << 16);
}

// ---------------- CSR build (union graph: nodes [0,N)=g1, [N,2N)=g2) ----------------

__global__ void histU_kernel(const int* __restrict__ d1, const int* __restrict__ d2,
                             int* __restrict__ cnt, int E, int N) {
    int i = blockIdx.x * blockDim.x + threadIdx.x;
    if (i < E) atomicAdd(&cnt[d1[i]], 1);
    else if (i < 2 * E) atomicAdd(&cnt[N + d2[i - E]], 1);
}

__global__ __launch_bounds__(256) void block_reduce_kernel(const int* __restrict__ cnt,
                                                           float* __restrict__ dinv,
                                                           int* __restrict__ blockSums, int NN) {
    int i = blockIdx.x * 256 + threadIdx.x;
    int v = 0;
    if (i < NN) {
        v = cnt[i];
        dinv[i] = 1.0f / sqrtf((float)(v + 1));  // +1 self loop
    }
    int s = v;
#pragma unroll
    for (int o = 32; o; o >>= 1) s += __shfl_down(s, o);
    __shared__ int ws[4];
    if ((threadIdx.x & 63) == 0) ws[threadIdx.x >> 6] = s;
    __syncthreads();
    if (threadIdx.x == 0) blockSums[blockIdx.x] = ws[0] + ws[1] + ws[2] + ws[3];
}

__global__ __launch_bounds__(1024) void scan_sums_kernel(const int* __restrict__ blockSums,
                                                         int* __restrict__ blockOff, int nb,
                                                         int* __restrict__ rowptr, int NN) {
    __shared__ int sh[1024];
    int t = threadIdx.x;
    int v = (t < nb) ? blockSums[t] : 0;
    sh[t] = v;
    __syncthreads();
    for (int o = 1; o < 1024; o <<= 1) {
        int u = (t >= o) ? sh[t - o] : 0;
        __syncthreads();
        sh[t] += u;
        __syncthreads();
    }
    if (t < nb) blockOff[t] = sh[t] - v;
    if (t == 1023) rowptr[NN] = sh[1023];
}

__global__ __launch_bounds__(256) void scan_write_kernel(const int* __restrict__ cnt,
                                                         const int* __restrict__ blockOff,
                                                         int* __restrict__ rowptr, int NN) {
    __shared__ int sh[256];
    int i = blockIdx.x * 256 + threadIdx.x;
    int t = threadIdx.x;
    int v = (i < NN) ? cnt[i] : 0;
    sh[t] = v;
    __syncthreads();
    for (int o = 1; o < 256; o <<= 1) {
        int u = (t >= o) ? sh[t - o] : 0;
        __syncthreads();
        sh[t] += u;
        __syncthreads();
    }
    if (i < NN) rowptr[i] = blockOff[blockIdx.x] + sh[t] - v;
}

__global__ void placeU_kernel(const int* __restrict__ s1, const int* __restrict__ d1,
                              const int* __restrict__ s2, const int* __restrict__ d2,
                              const int* __restrict__ rowptr, int* __restrict__ cnt,
                              int* __restrict__ csr, int E, int N) {
    int i = blockIdx.x * blockDim.x + threadIdx.x;
    int s, d;
    if (i < E)          { s = s1[i];         d = d1[i]; }
    else if (i < 2 * E) { s = s2[i - E] + N; d = d2[i - E] + N; }
    else return;
    int p = atomicSub(&cnt[d], 1);  // old count, 1..deg; drains cnt to 0
    csr[rowptr[d] + p - 1] = s;
}

// ---------------- Weight prep: W[K][128] f32 -> WhT/WlT [128][K] bf16 ----------------

__global__ void prep_weights(const float* __restrict__ W0, const float* __restrict__ W1,
                             const float* __restrict__ W2,
                             unsigned short* __restrict__ W0h, unsigned short* __restrict__ W0l,
                             unsigned short* __restrict__ W1h, unsigned short* __restrict__ W1l,
                             unsigned short* __restrict__ W2h, unsigned short* __restrict__ W2l) {
    const float* W; unsigned short *Wh, *Wl; int K;
    if (blockIdx.x == 0)      { W = W0; Wh = W0h; Wl = W0l; K = 64; }
    else if (blockIdx.x == 1) { W = W1; Wh = W1h; Wl = W1l; K = 128; }
    else                      { W = W2; Wh = W2h; Wl = W2l; K = 128; }
    for (int i = threadIdx.x; i < K * 128; i += 256) {
        int k = i >> 7, c = i & 127;
        float v = W[i];
        unsigned short h = f2bf(v);
        unsigned short l = f2bf(v - bf2f(h));
        Wh[c * K + k] = h;
        Wl[c * K + k] = l;
    }
}

// ---- Prescale: X0[i] = dinv[i] * x(i), unified [NN][64] f32 (coalesced) ----

__global__ void prescale_kernel(const float* __restrict__ x1, const float* __restrict__ x2,
                                const float* __restrict__ dinv, float* __restrict__ X0, int NN,
                                int N) {
    int i = blockIdx.x * blockDim.x + threadIdx.x;  // over NN*16 float4
    if (i >= NN * 16) return;
    int r = i >> 4;
    const float4* src = (r < N) ? (const float4*)(x1) + i
                                : (const float4*)(x2) + (i - N * 16);
    float4 v = *src;
    float d = dinv[r];
    v.x *= d; v.y *= d; v.z *= d; v.w *= d;
    reinterpret_cast<float4*>(X0)[i] = v;
}

// ---- Fused agg + MFMA GEMM (K=64). Block = 64 rows, 512 thr = 8 waves. ----

__global__ __launch_bounds__(512) void fused64_agg_gemm(
    const float* __restrict__ X, const int* __restrict__ rowptr,
    const int* __restrict__ csr,
    const unsigned short* __restrict__ WhT, const unsigned short* __restrict__ WlT,
    const float* __restrict__ bias, const float* __restrict__ dinv, int post,
    float* __restrict__ C, int M) {
    const int K = 64;
    const int LDA = K + 8;
    __shared__ unsigned short ldsH[64 * LDA];
    __shared__ unsigned short ldsL[64 * LDA];

    int t = threadIdx.x;
    int lane = t & 63, wid = t >> 6;
    int row0 = blockIdx.x * 64;

    // ---------- phase 1: aggregation (8 nodes per wave) ----------
    for (int rr = 0; rr < 8; ++rr) {
        int row = wid * 8 + rr;
        int g = row0 + row; if (g >= M) g = M - 1;
        int beg = rowptr[g], end = rowptr[g + 1];
        float acc = X[(size_t)g * 64 + lane];
        int e = beg;
        while (end - e >= 12) {  // 12-deep clean batches
            int s0 = csr[e], s1 = csr[e + 1], s2 = csr[e + 2], s3 = csr[e + 3];
            int s4 = csr[e + 4], s5 = csr[e + 5], s6 = csr[e + 6], s7 = csr[e + 7];
            int s8 = csr[e + 8], s9 = csr[e + 9], sa = csr[e + 10], sb = csr[e + 11];
            float v0 = X[(size_t)s0 * 64 + lane];
            float v1 = X[(size_t)s1 * 64 + lane];
            float v2 = X[(size_t)s2 * 64 + lane];
            float v3 = X[(size_t)s3 * 64 + lane];
            float v4 = X[(size_t)s4 * 64 + lane];
            float v5 = X[(size_t)s5 * 64 + lane];
            float v6 = X[(size_t)s6 * 64 + lane];
            float v7 = X[(size_t)s7 * 64 + lane];
            float v8 = X[(size_t)s8 * 64 + lane];
            float v9 = X[(size_t)s9 * 64 + lane];
            float va = X[(size_t)sa * 64 + lane];
            float vb = X[(size_t)sb * 64 + lane];
            acc += (((v0 + v1) + (v2 + v3)) + ((v4 + v5) + (v6 + v7))) +
                   (((v8 + v9) + (va + vb)));
            e += 12;
        }
        if (end - e >= 8) {
            int s0 = csr[e], s1 = csr[e + 1], s2 = csr[e + 2], s3 = csr[e + 3];
            int s4 = csr[e + 4], s5 = csr[e + 5], s6 = csr[e + 6], s7 = csr[e + 7];
            float v0 = X[(size_t)s0 * 64 + lane];
            float v1 = X[(size_t)s1 * 64 + lane];
            float v2 = X[(size_t)s2 * 64 + lane];
            float v3 = X[(size_t)s3 * 64 + lane];
            float v4 = X[(size_t)s4 * 64 + lane];
            float v5 = X[(size_t)s5 * 64 + lane];
            float v6 = X[(size_t)s6 * 64 + lane];
            float v7 = X[(size_t)s7 * 64 + lane];
            acc += ((v0 + v1) + (v2 + v3)) + ((v4 + v5) + (v6 + v7));
            e += 8;
        }
        if (e < end) {  // masked batch keeps up to 7 gathers in flight
#pragma unroll
            for (int j = 0; j < 7; ++j) {
                int a = e + j;
                bool vld = a < end;
                int s = csr[vld ? a : beg];
                float m = vld ? 1.f : 0.f;
                acc += m * X[(size_t)s * 64 + lane];
            }
        }
        unsigned short h = f2bf(acc);
        ldsH[row * LDA + lane] = h;
        ldsL[row * LDA + lane] = f2bf(acc - bf2f(h));
    }
    __syncthreads();

    // ---------- phase 2: MFMA GEMM from LDS ----------
    int c16 = lane & 15, kq = (lane >> 4) * 8;
    int col = wid * 16 + c16;

    bf16x8 wh[K / 32], wl[K / 32];
#pragma unroll
    for (int ks = 0; ks < K / 32; ++ks) {
        wh[ks] = *reinterpret_cast<const bf16x8*>(WhT + (size_t)col * K + ks * 32 + kq);
        wl[ks] = *reinterpret_cast<const bf16x8*>(WlT + (size_t)col * K + ks * 32 + kq);
    }
    float bb = bias[col];

#pragma unroll
    for (int rt = 0; rt < 4; ++rt) {
        f32x4 acc = {0.f, 0.f, 0.f, 0.f};
        int abase = (rt * 16 + c16) * LDA + kq;
#pragma unroll
        for (int ks = 0; ks < K / 32; ++ks) {
            bf16x8 ah = *reinterpret_cast<const bf16x8*>(ldsH + abase + ks * 32);
            bf16x8 al = *reinterpret_cast<const bf16x8*>(ldsL + abase + ks * 32);
            acc = __builtin_amdgcn_mfma_f32_16x16x32_bf16(ah, wh[ks], acc, 0, 0, 0);
            acc = __builtin_amdgcn_mfma_f32_16x16x32_bf16(ah, wl[ks], acc, 0, 0, 0);
            acc = __builtin_amdgcn_mfma_f32_16x16x32_bf16(al, wh[ks], acc, 0, 0, 0);
        }
#pragma unroll
        for (int r = 0; r < 4; ++r) {
            int gr = row0 + rt * 16 + (lane >> 4) * 4 + r;
            if (gr < M) {
                float d = dinv[gr];
                float po = post ? d : 1.0f;
                float v = fmaxf(acc[r] * d + bb, 0.f) * po;
                C[(size_t)gr * 128 + col] = v;
            }
        }
    }
}

// ---- Fused agg + MFMA GEMM (K=128). Same structure, float2 gathers. ----

__global__ __launch_bounds__(512) void fused128_agg_gemm(
    const float* __restrict__ X, const int* __restrict__ rowptr,
    const int* __restrict__ csr,
    const unsigned short* __restrict__ WhT, const unsigned short* __restrict__ WlT,
    const float* __restrict__ bias, const float* __restrict__ dinv, int post,
    float* __restrict__ C, int M) {
    const int K = 128;
    const int LDA = K + 8;
    __shared__ unsigned short ldsH[64 * LDA];
    __shared__ unsigned short ldsL[64 * LDA];

    int t = threadIdx.x;
    int lane = t & 63, wid = t >> 6;
    int row0 = blockIdx.x * 64;

    const float2* X2 = (const float2*)X;

    // ---------- phase 1: aggregation (8 nodes per wave) ----------
    for (int rr = 0; rr < 8; ++rr) {
        int row = wid * 8 + rr;
        int g = row0 + row; if (g >= M) g = M - 1;
        int beg = rowptr[g], end = rowptr[g + 1];
        float2 self = X2[(size_t)g * 64 + lane];
        float ax = self.x, ay = self.y;
        int e = beg;
        while (end - e >= 12) {  // 12-deep clean batches
            int s0 = csr[e], s1 = csr[e + 1], s2 = csr[e + 2], s3 = csr[e + 3];
            int s4 = csr[e + 4], s5 = csr[e + 5], s6 = csr[e + 6], s7 = csr[e + 7];
            int s8 = csr[e + 8], s9 = csr[e + 9], sa = csr[e + 10], sb = csr[e + 11];
            float2 v0 = X2[(size_t)s0 * 64 + lane];
            float2 v1 = X2[(size_t)s1 * 64 + lane];
            float2 v2 = X2[(size_t)s2 * 64 + lane];
            float2 v3 = X2[(size_t)s3 * 64 + lane];
            float2 v4 = X2[(size_t)s4 * 64 + lane];
            float2 v5 = X2[(size_t)s5 * 64 + lane];
            float2 v6 = X2[(size_t)s6 * 64 + lane];
            float2 v7 = X2[(size_t)s7 * 64 + lane];
            float2 v8 = X2[(size_t)s8 * 64 + lane];
            float2 v9 = X2[(size_t)s9 * 64 + lane];
            float2 va = X2[(size_t)sa * 64 + lane];
            float2 vb = X2[(size_t)sb * 64 + lane];
            ax += (((v0.x + v1.x) + (v2.x + v3.x)) + ((v4.x + v5.x) + (v6.x + v7.x))) +
                  ((v8.x + v9.x) + (va.x + vb.x));
            ay += (((v0.y + v1.y) + (v2.y + v3.y)) + ((v4.y + v5.y) + (v6.y + v7.y))) +
                  ((v8.y + v9.y) + (va.y + vb.y));
            e += 12;
        }
        if (end - e >= 8) {
            int s0 = csr[e], s1 = csr[e + 1], s2 = csr[e + 2], s3 = csr[e + 3];
            int s4 = csr[e + 4], s5 = csr[e + 5], s6 = csr[e + 6], s7 = csr[e + 7];
            float2 v0 = X2[(size_t)s0 * 64 + lane];
            float2 v1 = X2[(size_t)s1 * 64 + lane];
            float2 v2 = X2[(size_t)s2 * 64 + lane];
            float2 v3 = X2[(size_t)s3 * 64 + lane];
            float2 v4 = X2[(size_t)s4 * 64 + lane];
            float2 v5 = X2[(size_t)s5 * 64 + lane];
            float2 v6 = X2[(size_t)s6 * 64 + lane];
            float2 v7 = X2[(size_t)s7 * 64 + lane];
            ax += ((v0.x + v1.x) + (v2.x + v3.x)) + ((v4.x + v5.x) + (v6.x + v7.x));
            ay += ((v0.y + v1.y) + (v2.y + v3.y)) + ((v4.y + v5.y) + (v6.y + v7.y));
            e += 8;
        }
        if (e < end) {
#pragma unroll
            for (int j = 0; j < 7; ++j) {
                int a = e + j;
                bool vld = a < end;
                int s = csr[vld ? a : beg];
                float m = vld ? 1.f : 0.f;
                float2 v = X2[(size_t)s * 64 + lane];
                ax += m * v.x; ay += m * v.y;
            }
        }
        unsigned short hx = f2bf(ax), hy = f2bf(ay);
        ushort2 H; H.x = hx; H.y = hy;
        ushort2 L; L.x = f2bf(ax - bf2f(hx)); L.y = f2bf(ay - bf2f(hy));
        *reinterpret_cast<ushort2*>(&ldsH[row * LDA + 2 * lane]) = H;
        *reinterpret_cast<ushort2*>(&ldsL[row * LDA + 2 * lane]) = L;
    }
    __syncthreads();

    // ---------- phase 2: MFMA GEMM from LDS ----------
    int c16 = lane & 15, kq = (lane >> 4) * 8;
    int col = wid * 16 + c16;

    bf16x8 wh[K / 32], wl[K / 32];
#pragma unroll
    for (int ks = 0; ks < K / 32; ++ks) {
        wh[ks] = *reinterpret_cast<const bf16x8*>(WhT + (size_t)col * K + ks * 32 + kq);
        wl[ks] = *reinterpret_cast<const bf16x8*>(WlT + (size_t)col * K + ks * 32 + kq);
    }
    float bb = bias[col];

#pragma unroll
    for (int rt = 0; rt < 4; ++rt) {
        f32x4 acc = {0.f, 0.f, 0.f, 0.f};
        int abase = (rt * 16 + c16) * LDA + kq;
#pragma unroll
        for (int ks = 0; ks < K / 32; ++ks) {
            bf16x8 ah = *reinterpret_cast<const bf16x8*>(ldsH + abase + ks * 32);
            bf16x8 al = *reinterpret_cast<const bf16x8*>(ldsL + abase + ks * 32);
            acc = __builtin_amdgcn_mfma_f32_16x16x32_bf16(ah, wh[ks], acc, 0, 0, 0);
            acc = __builtin_amdgcn_mfma_f32_16x16x32_bf16(ah, wl[ks], acc, 0, 0, 0);
            acc = __builtin_amdgcn_mfma_f32_16x16x32_bf16(al, wh[ks], acc, 0, 0, 0);
        }
#pragma unroll
        for (int r = 0; r < 4; ++r) {
            int gr = row0 + rt * 16 + (lane >> 4) * 4 + r;
            if (gr < M) {
                float d = dinv[gr];
                float po = post ? d : 1.0f;
                float v = fmaxf(acc[r] * d + bb, 0.f) * po;
                C[(size_t)gr * 128 + col] = v;
            }
        }
    }
}

// ---------------- Final FC ----------------

__global__ void fc_kernel(const float* __restrict__ H3, const int* __restrict__ label,
                          const float* __restrict__ fcW, const float* __restrict__ fcb,
                          float* __restrict__ out, int P, int N) {
    int w = blockIdx.x * (blockDim.x >> 6) + (threadIdx.x >> 6);
    int lane = threadIdx.x & 63;
    if (w >= P) return;
    int l0 = label[2 * w], l1 = label[2 * w + 1] + N;
    float xl0 = H3[(size_t)l0 * 128 + lane];
    float xl1 = H3[(size_t)l0 * 128 + 64 + lane];
    float xr0 = H3[(size_t)l1 * 128 + lane];
    float xr1 = H3[(size_t)l1 * 128 + 64 + lane];
    float a0 = xl0 * fcW[lane * 2]             + xl1 * fcW[(64 + lane) * 2]
             + xr0 * fcW[(128 + lane) * 2]     + xr1 * fcW[(192 + lane) * 2];
    float a1 = xl0 * fcW[lane * 2 + 1]         + xl1 * fcW[(64 + lane) * 2 + 1]
             + xr0 * fcW[(128 + lane) * 2 + 1] + xr1 * fcW[(192 + lane) * 2 + 1];
#pragma unroll
    for (int o = 32; o; o >>= 1) {
        a0 += __shfl_xor(a0, o);
        a1 += __shfl_xor(a1, o);
    }
    if (lane == 0) {
        out[2 * w]     = fmaxf(a0 + fcb[0], 0.f);
        out[2 * w + 1] = fmaxf(a1 + fcb[1], 0.f);
    }
}

// ---------------- launch ----------------

extern "C" void kernel_launch(void* const* d_in, const int* in_sizes, int n_in,
                              void* d_out, int out_size, void* d_ws, size_t ws_size,
                              hipStream_t stream) {
    const float* x1   = (const float*)d_in[0];
    const int*   e1   = (const int*)d_in[1];
    const float* x2   = (const float*)d_in[2];
    const int*   e2   = (const int*)d_in[3];
    const int*   label= (const int*)d_in[4];
    const float* W0   = (const float*)d_in[5];
    const float* b0   = (const float*)d_in[6];
    const float* W1   = (const float*)d_in[7];
    const float* b1   = (const float*)d_in[8];
    const float* W2   = (const float*)d_in[9];
    const float* b2   = (const float*)d_in[10];
    const float* fcW  = (const float*)d_in[11];
    const float* fcb  = (const float*)d_in[12];
    float* out = (float*)d_out;

    const int N = in_sizes[0] / 64;
    const int E = in_sizes[1] / 2;
    const int P = in_sizes[4] / 2;
    const int NN = 2 * N;
    const int NB = (NN + 255) / 256;
    const int GB = (NN + 63) / 64;  // fused blocks (64 rows each)

    char* ws = (char*)d_ws;
    size_t off = 0;
    auto alloc = [&](size_t bytes) -> void* {
        void* p = ws + off;
        off += (bytes + 255) & ~(size_t)255;
        return p;
    };
    int*   cnt      = (int*)alloc((size_t)NN * 4);
    int*   rowptr   = (int*)alloc((size_t)(NN + 1) * 4);
    float* dinv     = (float*)alloc((size_t)NN * 4);
    int*   csr      = (int*)alloc((size_t)2 * E * 4);
    int*   blockSums= (int*)alloc((size_t)NB * 4);
    int*   blockOff = (int*)alloc((size_t)NB * 4);
    float* bufA     = (float*)alloc((size_t)NN * 128 * 4);  // X0 ([NN][64]) then H2
    float* bufB     = (float*)alloc((size_t)NN * 128 * 4);  // H1 then H3
    unsigned short* W0h = (unsigned short*)alloc(64 * 128 * 2);
    unsigned short* W0l = (unsigned short*)alloc(64 * 128 * 2);
    unsigned short* W1h = (unsigned short*)alloc(128 * 128 * 2);
    unsigned short* W1l = (unsigned short*)alloc(128 * 128 * 2);
    unsigned short* W2h = (unsigned short*)alloc(128 * 128 * 2);
    unsigned short* W2l = (unsigned short*)alloc(128 * 128 * 2);

    prep_weights<<<3, 256, 0, stream>>>(W0, W1, W2, W0h, W0l, W1h, W1l, W2h, W2l);

    // CSR build (once, union graph)
    hipMemsetAsync(cnt, 0, (size_t)NN * 4, stream);
    histU_kernel<<<(2 * E + 255) / 256, 256, 0, stream>>>(e1 + E, e2 + E, cnt, E, N);
    block_reduce_kernel<<<NB, 256, 0, stream>>>(cnt, dinv, blockSums, NN);
    scan_sums_kernel<<<1, 1024, 0, stream>>>(blockSums, blockOff, NB, rowptr, NN);
    scan_write_kernel<<<NB, 256, 0, stream>>>(cnt, blockOff, rowptr, NN);
    placeU_kernel<<<(2 * E + 255) / 256, 256, 0, stream>>>(e1, e1 + E, e2, e2 + E,
                                                           rowptr, cnt, csr, E, N);
    // layer 0: prescale into X0 (bufA), fused agg+GEMM 64->128 into bufB
    prescale_kernel<<<(NN * 16 + 255) / 256, 256, 0, stream>>>(x1, x2, dinv, bufA, NN, N);
    fused64_agg_gemm<<<GB, 512, 0, stream>>>(bufA, rowptr, csr, W0h, W0l, b0, dinv, 1,
                                             bufB, NN);
    // layer 1: bufB -> bufA
    fused128_agg_gemm<<<GB, 512, 0, stream>>>(bufB, rowptr, csr, W1h, W1l, b1, dinv, 1,
                                              bufA, NN);
    // layer 2 (no post-scale): bufA -> bufB (H3)
    fused128_agg_gemm<<<GB, 512, 0, stream>>>(bufA, rowptr, csr, W2h, W2l, b2, dinv, 0,
                                              bufB, NN);

    fc_kernel<<<(P + 3) / 4, 256, 0, stream>>>(bufB, label, fcW, fcb, out, P, N);
}

// Round 11
// 539.718 us; speedup vs baseline: 3.6315x; 1.0359x over previous
//
#include <hip/hip_runtime.h>
#include <math.h>

typedef __attribute__((ext_vector_type(8))) short bf16x8;
typedef __attribute__((ext_vector_type(4))) float f32x4;

__device__ inline unsigned short f2bf(float f) {
    unsigned int u = __float_as_uint(f);
    unsigned int r = u + 0x7fffu + ((u >> 16) & 1u);
    return (unsigned short)(r >> 16);
}
__device__ inline float bf2f(unsigned short b) {
    return __uint_as_float(((unsigned int)b) << 16);
}

// ---------------- CSR build (union graph: nodes [0,N)=g1, [N,2N)=g2) ----------------

__global__ void histU_kernel(const int* __restrict__ d1, const int* __restrict__ d2,
                             int* __restrict__ cnt, int E, int N) {
    int i = blockIdx.x * blockDim.x + threadIdx.x;
    if (i < E) atomicAdd(&cnt[d1[i]], 1);
    else if (i < 2 * E) atomicAdd(&cnt[N + d2[i - E]], 1);
}

__global__ __launch_bounds__(256) void block_reduce_kernel(const int* __restrict__ cnt,
                                                           float* __restrict__ dinv,
                                                           int* __restrict__ blockSums, int NN) {
    int i = blockIdx.x * 256 + threadIdx.x;
    int v = 0;
    if (i < NN) {
        v = cnt[i];
        dinv[i] = 1.0f / sqrtf((float)(v + 1));  // +1 self loop
    }
    int s = v;
#pragma unroll
    for (int o = 32; o; o >>= 1) s += __shfl_down(s, o);
    __shared__ int ws[4];
    if ((threadIdx.x & 63) == 0) ws[threadIdx.x >> 6] = s;
    __syncthreads();
    if (threadIdx.x == 0) blockSums[blockIdx.x] = ws[0] + ws[1] + ws[2] + ws[3];
}

__global__ __launch_bounds__(1024) void scan_sums_kernel(const int* __restrict__ blockSums,
                                                         int* __restrict__ blockOff, int nb,
                                                         int* __restrict__ rowptr, int NN) {
    __shared__ int sh[1024];
    int t = threadIdx.x;
    int v = (t < nb) ? blockSums[t] : 0;
    sh[t] = v;
    __syncthreads();
    for (int o = 1; o < 1024; o <<= 1) {
        int u = (t >= o) ? sh[t - o] : 0;
        __syncthreads();
        sh[t] += u;
        __syncthreads();
    }
    if (t < nb) blockOff[t] = sh[t] - v;
    if (t == 1023) rowptr[NN] = sh[1023];
}

__global__ __launch_bounds__(256) void scan_write_kernel(const int* __restrict__ cnt,
                                                         const int* __restrict__ blockOff,
                                                         int* __restrict__ rowptr, int NN) {
    __shared__ int sh[256];
    int i = blockIdx.x * 256 + threadIdx.x;
    int t = threadIdx.x;
    int v = (i < NN) ? cnt[i] : 0;
    sh[t] = v;
    __syncthreads();
    for (int o = 1; o < 256; o <<= 1) {
        int u = (t >= o) ? sh[t - o] : 0;
        __syncthreads();
        sh[t] += u;
        __syncthreads();
    }
    if (i < NN) rowptr[i] = blockOff[blockIdx.x] + sh[t] - v;
}

__global__ void placeU_kernel(const int* __restrict__ s1, const int* __restrict__ d1,
                              const int* __restrict__ s2, const int* __restrict__ d2,
                              const int* __restrict__ rowptr, int* __restrict__ cnt,
                              int* __restrict__ csr, int E, int N) {
    int i = blockIdx.x * blockDim.x + threadIdx.x;
    int s, d;
    if (i < E)          { s = s1[i];         d = d1[i]; }
    else if (i < 2 * E) { s = s2[i - E] + N; d = d2[i - E] + N; }
    else return;
    int p = atomicSub(&cnt[d], 1);  // old count, 1..deg; drains cnt to 0
    csr[rowptr[d] + p - 1] = s;
}

// ---------------- Weight prep: W[K][128] f32 -> WhT/WlT [128][K] bf16 ----------------

__global__ void prep_weights(const float* __restrict__ W0, const float* __restrict__ W1,
                             const float* __restrict__ W2,
                             unsigned short* __restrict__ W0h, unsigned short* __restrict__ W0l,
                             unsigned short* __restrict__ W1h, unsigned short* __restrict__ W1l,
                             unsigned short* __restrict__ W2h, unsigned short* __restrict__ W2l) {
    const float* W; unsigned short *Wh, *Wl; int K;
    if (blockIdx.x == 0)      { W = W0; Wh = W0h; Wl = W0l; K = 64; }
    else if (blockIdx.x == 1) { W = W1; Wh = W1h; Wl = W1l; K = 128; }
    else                      { W = W2; Wh = W2h; Wl = W2l; K = 128; }
    for (int i = threadIdx.x; i < K * 128; i += 256) {
        int k = i >> 7, c = i & 127;
        float v = W[i];
        unsigned short h = f2bf(v);
        unsigned short l = f2bf(v - bf2f(h));
        Wh[c * K + k] = h;
        Wl[c * K + k] = l;
    }
}

// ---- Prescale: X0[i] = dinv[i] * x(i), unified [NN][64] f32 (coalesced) ----

__global__ void prescale_kernel(const float* __restrict__ x1, const float* __restrict__ x2,
                                const float* __restrict__ dinv, float* __restrict__ X0, int NN,
                                int N) {
    int i = blockIdx.x * blockDim.x + threadIdx.x;  // over NN*16 float4
    if (i >= NN * 16) return;
    int r = i >> 4;
    const float4* src = (r < N) ? (const float4*)(x1) + i
                                : (const float4*)(x2) + (i - N * 16);
    float4 v = *src;
    float d = dinv[r];
    v.x *= d; v.y *= d; v.z *= d; v.w *= d;
    reinterpret_cast<float4*>(X0)[i] = v;
}

// ---- Fused agg + MFMA GEMM (K=64). Block = 64 rows, 512 thr = 8 waves.
// Gather: 4 nodes per wave (16-lane groups, float4/lane = full 64-f32 row per group).

__global__ __launch_bounds__(512) void fused64_agg_gemm(
    const float* __restrict__ X, const int* __restrict__ rowptr,
    const int* __restrict__ csr,
    const unsigned short* __restrict__ WhT, const unsigned short* __restrict__ WlT,
    const float* __restrict__ bias, const float* __restrict__ dinv, int post,
    float* __restrict__ C, int M) {
    const int K = 64;
    const int LDA = K + 8;
    __shared__ unsigned short ldsH[64 * LDA];
    __shared__ unsigned short ldsL[64 * LDA];

    int t = threadIdx.x;
    int lane = t & 63, wid = t >> 6;
    int row0 = blockIdx.x * 64;

    const float4* X4 = (const float4*)X;  // 16 float4 per row
    int grp = lane >> 4;   // 0..3
    int fl = lane & 15;    // features fl*4 .. fl*4+3

    // ---------- phase 1: aggregation (4 nodes per wave pass, 2 passes) ----------
    for (int rr = 0; rr < 2; ++rr) {
        int row = wid * 8 + rr * 4 + grp;
        int g = row0 + row; if (g >= M) g = M - 1;
        int beg = rowptr[g], end = rowptr[g + 1];
        float4 s4 = X4[(size_t)g * 16 + fl];
        float a0 = s4.x, a1 = s4.y, a2 = s4.z, a3 = s4.w;
        int e = beg;
        while (end - e >= 8) {  // per-group divergence via exec mask; loads stay clean
            int s0 = csr[e], s1 = csr[e + 1], s2 = csr[e + 2], s3 = csr[e + 3];
            int s4i = csr[e + 4], s5 = csr[e + 5], s6 = csr[e + 6], s7 = csr[e + 7];
            float4 v0 = X4[(size_t)s0 * 16 + fl];
            float4 v1 = X4[(size_t)s1 * 16 + fl];
            float4 v2 = X4[(size_t)s2 * 16 + fl];
            float4 v3 = X4[(size_t)s3 * 16 + fl];
            float4 v4 = X4[(size_t)s4i * 16 + fl];
            float4 v5 = X4[(size_t)s5 * 16 + fl];
            float4 v6 = X4[(size_t)s6 * 16 + fl];
            float4 v7 = X4[(size_t)s7 * 16 + fl];
            a0 += ((v0.x + v1.x) + (v2.x + v3.x)) + ((v4.x + v5.x) + (v6.x + v7.x));
            a1 += ((v0.y + v1.y) + (v2.y + v3.y)) + ((v4.y + v5.y) + (v6.y + v7.y));
            a2 += ((v0.z + v1.z) + (v2.z + v3.z)) + ((v4.z + v5.z) + (v6.z + v7.z));
            a3 += ((v0.w + v1.w) + (v2.w + v3.w)) + ((v4.w + v5.w) + (v6.w + v7.w));
            e += 8;
        }
        if (e < end) {  // masked tail, up to 7 in flight
#pragma unroll
            for (int j = 0; j < 7; ++j) {
                int a = e + j;
                bool vld = a < end;
                int s = csr[vld ? a : beg];
                float m = vld ? 1.f : 0.f;
                float4 v = X4[(size_t)s * 16 + fl];
                a0 += m * v.x; a1 += m * v.y; a2 += m * v.z; a3 += m * v.w;
            }
        }
        ushort4 H, L;
        H.x = f2bf(a0); L.x = f2bf(a0 - bf2f(H.x));
        H.y = f2bf(a1); L.y = f2bf(a1 - bf2f(H.y));
        H.z = f2bf(a2); L.z = f2bf(a2 - bf2f(H.z));
        H.w = f2bf(a3); L.w = f2bf(a3 - bf2f(H.w));
        *reinterpret_cast<ushort4*>(&ldsH[row * LDA + fl * 4]) = H;
        *reinterpret_cast<ushort4*>(&ldsL[row * LDA + fl * 4]) = L;
    }
    __syncthreads();

    // ---------- phase 2: MFMA GEMM from LDS ----------
    int c16 = lane & 15, kq = (lane >> 4) * 8;
    int col = wid * 16 + c16;

    bf16x8 wh[K / 32], wl[K / 32];
#pragma unroll
    for (int ks = 0; ks < K / 32; ++ks) {
        wh[ks] = *reinterpret_cast<const bf16x8*>(WhT + (size_t)col * K + ks * 32 + kq);
        wl[ks] = *reinterpret_cast<const bf16x8*>(WlT + (size_t)col * K + ks * 32 + kq);
    }
    float bb = bias[col];

#pragma unroll
    for (int rt = 0; rt < 4; ++rt) {
        f32x4 acc = {0.f, 0.f, 0.f, 0.f};
        int abase = (rt * 16 + c16) * LDA + kq;
#pragma unroll
        for (int ks = 0; ks < K / 32; ++ks) {
            bf16x8 ah = *reinterpret_cast<const bf16x8*>(ldsH + abase + ks * 32);
            bf16x8 al = *reinterpret_cast<const bf16x8*>(ldsL + abase + ks * 32);
            acc = __builtin_amdgcn_mfma_f32_16x16x32_bf16(ah, wh[ks], acc, 0, 0, 0);
            acc = __builtin_amdgcn_mfma_f32_16x16x32_bf16(ah, wl[ks], acc, 0, 0, 0);
            acc = __builtin_amdgcn_mfma_f32_16x16x32_bf16(al, wh[ks], acc, 0, 0, 0);
        }
#pragma unroll
        for (int r = 0; r < 4; ++r) {
            int gr = row0 + rt * 16 + (lane >> 4) * 4 + r;
            if (gr < M) {
                float d = dinv[gr];
                float po = post ? d : 1.0f;
                float v = fmaxf(acc[r] * d + bb, 0.f) * po;
                C[(size_t)gr * 128 + col] = v;
            }
        }
    }
}

// ---- Fused agg + MFMA GEMM (K=128). Gather: 2 nodes per wave (32-lane groups, float4). ----

__global__ __launch_bounds__(512) void fused128_agg_gemm(
    const float* __restrict__ X, const int* __restrict__ rowptr,
    const int* __restrict__ csr,
    const unsigned short* __restrict__ WhT, const unsigned short* __restrict__ WlT,
    const float* __restrict__ bias, const float* __restrict__ dinv, int post,
    float* __restrict__ C, int M) {
    const int K = 128;
    const int LDA = K + 8;
    __shared__ unsigned short ldsH[64 * LDA];
    __shared__ unsigned short ldsL[64 * LDA];

    int t = threadIdx.x;
    int lane = t & 63, wid = t >> 6;
    int row0 = blockIdx.x * 64;

    const float4* X4 = (const float4*)X;  // 32 float4 per row
    int grp = lane >> 5;   // 0..1
    int fl = lane & 31;    // features fl*4 .. fl*4+3

    // ---------- phase 1: aggregation (2 nodes per wave pass, 4 passes) ----------
    for (int rr = 0; rr < 4; ++rr) {
        int row = wid * 8 + rr * 2 + grp;
        int g = row0 + row; if (g >= M) g = M - 1;
        int beg = rowptr[g], end = rowptr[g + 1];
        float4 s4 = X4[(size_t)g * 32 + fl];
        float a0 = s4.x, a1 = s4.y, a2 = s4.z, a3 = s4.w;
        int e = beg;
        while (end - e >= 8) {  // per-group divergence via exec mask; loads stay clean
            int s0 = csr[e], s1 = csr[e + 1], s2 = csr[e + 2], s3 = csr[e + 3];
            int s4i = csr[e + 4], s5 = csr[e + 5], s6 = csr[e + 6], s7 = csr[e + 7];
            float4 v0 = X4[(size_t)s0 * 32 + fl];
            float4 v1 = X4[(size_t)s1 * 32 + fl];
            float4 v2 = X4[(size_t)s2 * 32 + fl];
            float4 v3 = X4[(size_t)s3 * 32 + fl];
            float4 v4 = X4[(size_t)s4i * 32 + fl];
            float4 v5 = X4[(size_t)s5 * 32 + fl];
            float4 v6 = X4[(size_t)s6 * 32 + fl];
            float4 v7 = X4[(size_t)s7 * 32 + fl];
            a0 += ((v0.x + v1.x) + (v2.x + v3.x)) + ((v4.x + v5.x) + (v6.x + v7.x));
            a1 += ((v0.y + v1.y) + (v2.y + v3.y)) + ((v4.y + v5.y) + (v6.y + v7.y));
            a2 += ((v0.z + v1.z) + (v2.z + v3.z)) + ((v4.z + v5.z) + (v6.z + v7.z));
            a3 += ((v0.w + v1.w) + (v2.w + v3.w)) + ((v4.w + v5.w) + (v6.w + v7.w));
            e += 8;
        }
        if (e < end) {
#pragma unroll
            for (int j = 0; j < 7; ++j) {
                int a = e + j;
                bool vld = a < end;
                int s = csr[vld ? a : beg];
                float m = vld ? 1.f : 0.f;
                float4 v = X4[(size_t)s * 32 + fl];
                a0 += m * v.x; a1 += m * v.y; a2 += m * v.z; a3 += m * v.w;
            }
        }
        ushort4 H, L;
        H.x = f2bf(a0); L.x = f2bf(a0 - bf2f(H.x));
        H.y = f2bf(a1); L.y = f2bf(a1 - bf2f(H.y));
        H.z = f2bf(a2); L.z = f2bf(a2 - bf2f(H.z));
        H.w = f2bf(a3); L.w = f2bf(a3 - bf2f(H.w));
        *reinterpret_cast<ushort4*>(&ldsH[row * LDA + fl * 4]) = H;
        *reinterpret_cast<ushort4*>(&ldsL[row * LDA + fl * 4]) = L;
    }
    __syncthreads();

    // ---------- phase 2: MFMA GEMM from LDS ----------
    int c16 = lane & 15, kq = (lane >> 4) * 8;
    int col = wid * 16 + c16;

    bf16x8 wh[K / 32], wl[K / 32];
#pragma unroll
    for (int ks = 0; ks < K / 32; ++ks) {
        wh[ks] = *reinterpret_cast<const bf16x8*>(WhT + (size_t)col * K + ks * 32 + kq);
        wl[ks] = *reinterpret_cast<const bf16x8*>(WlT + (size_t)col * K + ks * 32 + kq);
    }
    float bb = bias[col];

#pragma unroll
    for (int rt = 0; rt < 4; ++rt) {
        f32x4 acc = {0.f, 0.f, 0.f, 0.f};
        int abase = (rt * 16 + c16) * LDA + kq;
#pragma unroll
        for (int ks = 0; ks < K / 32; ++ks) {
            bf16x8 ah = *reinterpret_cast<const bf16x8*>(ldsH + abase + ks * 32);
            bf16x8 al = *reinterpret_cast<const bf16x8*>(ldsL + abase + ks * 32);
            acc = __builtin_amdgcn_mfma_f32_16x16x32_bf16(ah, wh[ks], acc, 0, 0, 0);
            acc = __builtin_amdgcn_mfma_f32_16x16x32_bf16(ah, wl[ks], acc, 0, 0, 0);
            acc = __builtin_amdgcn_mfma_f32_16x16x32_bf16(al, wh[ks], acc, 0, 0, 0);
        }
#pragma unroll
        for (int r = 0; r < 4; ++r) {
            int gr = row0 + rt * 16 + (lane >> 4) * 4 + r;
            if (gr < M) {
                float d = dinv[gr];
                float po = post ? d : 1.0f;
                float v = fmaxf(acc[r] * d + bb, 0.f) * po;
                C[(size_t)gr * 128 + col] = v;
            }
        }
    }
}

// ---------------- Final FC ----------------

__global__ void fc_kernel(const float* __restrict__ H3, const int* __restrict__ label,
                          const float* __restrict__ fcW, const float* __restrict__ fcb,
                          float* __restrict__ out, int P, int N) {
    int w = blockIdx.x * (blockDim.x >> 6) + (threadIdx.x >> 6);
    int lane = threadIdx.x & 63;
    if (w >= P) return;
    int l0 = label[2 * w], l1 = label[2 * w + 1] + N;
    float xl0 = H3[(size_t)l0 * 128 + lane];
    float xl1 = H3[(size_t)l0 * 128 + 64 + lane];
    float xr0 = H3[(size_t)l1 * 128 + lane];
    float xr1 = H3[(size_t)l1 * 128 + 64 + lane];
    float a0 = xl0 * fcW[lane * 2]             + xl1 * fcW[(64 + lane) * 2]
             + xr0 * fcW[(128 + lane) * 2]     + xr1 * fcW[(192 + lane) * 2];
    float a1 = xl0 * fcW[lane * 2 + 1]         + xl1 * fcW[(64 + lane) * 2 + 1]
             + xr0 * fcW[(128 + lane) * 2 + 1] + xr1 * fcW[(192 + lane) * 2 + 1];
#pragma unroll
    for (int o = 32; o; o >>= 1) {
        a0 += __shfl_xor(a0, o);
        a1 += __shfl_xor(a1, o);
    }
    if (lane == 0) {
        out[2 * w]     = fmaxf(a0 + fcb[0], 0.f);
        out[2 * w + 1] = fmaxf(a1 + fcb[1], 0.f);
    }
}

// ---------------- launch ----------------

extern "C" void kernel_launch(void* const* d_in, const int* in_sizes, int n_in,
                              void* d_out, int out_size, void* d_ws, size_t ws_size,
                              hipStream_t stream) {
    const float* x1   = (const float*)d_in[0];
    const int*   e1   = (const int*)d_in[1];
    const float* x2   = (const float*)d_in[2];
    const int*   e2   = (const int*)d_in[3];
    const int*   label= (const int*)d_in[4];
    const float* W0   = (const float*)d_in[5];
    const float* b0   = (const float*)d_in[6];
    const float* W1   = (const float*)d_in[7];
    const float* b1   = (const float*)d_in[8];
    const float* W2   = (const float*)d_in[9];
    const float* b2   = (const float*)d_in[10];
    const float* fcW  = (const float*)d_in[11];
    const float* fcb  = (const float*)d_in[12];
    float* out = (float*)d_out;

    const int N = in_sizes[0] / 64;
    const int E = in_sizes[1] / 2;
    const int P = in_sizes[4] / 2;
    const int NN = 2 * N;
    const int NB = (NN + 255) / 256;
    const int GB = (NN + 63) / 64;  // fused blocks (64 rows each)

    char* ws = (char*)d_ws;
    size_t off = 0;
    auto alloc = [&](size_t bytes) -> void* {
        void* p = ws + off;
        off += (bytes + 255) & ~(size_t)255;
        return p;
    };
    int*   cnt      = (int*)alloc((size_t)NN * 4);
    int*   rowptr   = (int*)alloc((size_t)(NN + 1) * 4);
    float* dinv     = (float*)alloc((size_t)NN * 4);
    int*   csr      = (int*)alloc((size_t)2 * E * 4);
    int*   blockSums= (int*)alloc((size_t)NB * 4);
    int*   blockOff = (int*)alloc((size_t)NB * 4);
    float* bufA     = (float*)alloc((size_t)NN * 128 * 4);  // X0 ([NN][64]) then H2
    float* bufB     = (float*)alloc((size_t)NN * 128 * 4);  // H1 then H3
    unsigned short* W0h = (unsigned short*)alloc(64 * 128 * 2);
    unsigned short* W0l = (unsigned short*)alloc(64 * 128 * 2);
    unsigned short* W1h = (unsigned short*)alloc(128 * 128 * 2);
    unsigned short* W1l = (unsigned short*)alloc(128 * 128 * 2);
    unsigned short* W2h = (unsigned short*)alloc(128 * 128 * 2);
    unsigned short* W2l = (unsigned short*)alloc(128 * 128 * 2);

    prep_weights<<<3, 256, 0, stream>>>(W0, W1, W2, W0h, W0l, W1h, W1l, W2h, W2l);

    // CSR build (once, union graph)
    hipMemsetAsync(cnt, 0, (size_t)NN * 4, stream);
    histU_kernel<<<(2 * E + 255) / 256, 256, 0, stream>>>(e1 + E, e2 + E, cnt, E, N);
    block_reduce_kernel<<<NB, 256, 0, stream>>>(cnt, dinv, blockSums, NN);
    scan_sums_kernel<<<1, 1024, 0, stream>>>(blockSums, blockOff, NB, rowptr, NN);
    scan_write_kernel<<<NB, 256, 0, stream>>>(cnt, blockOff, rowptr, NN);
    placeU_kernel<<<(2 * E + 255) / 256, 256, 0, stream>>>(e1, e1 + E, e2, e2 + E,
                                                           rowptr, cnt, csr, E, N);
    // layer 0: prescale into X0 (bufA), fused agg+GEMM 64->128 into bufB
    prescale_kernel<<<(NN * 16 + 255) / 256, 256, 0, stream>>>(x1, x2, dinv, bufA, NN, N);
    fused64_agg_gemm<<<GB, 512, 0, stream>>>(bufA, rowptr, csr, W0h, W0l, b0, dinv, 1,
                                             bufB, NN);
    // layer 1: bufB -> bufA
    fused128_agg_gemm<<<GB, 512, 0, stream>>>(bufB, rowptr, csr, W1h, W1l, b1, dinv, 1,
                                              bufA, NN);
    // layer 2 (no post-scale): bufA -> bufB (H3)
    fused128_agg_gemm<<<GB, 512, 0, stream>>>(bufA, rowptr, csr, W2h, W2l, b2, dinv, 0,
                                              bufB, NN);

    fc_kernel<<<(P + 3) / 4, 256, 0, stream>>>(bufB, label, fcW, fcb, out, P, N);
}